// Round 11
// baseline (410.270 us; speedup 1.0000x reference)
//
#include <hip/hip_runtime.h>
#include <math.h>

#define HW   16384           // 128*128
#define PS   16900           // 130*130 padded plane

typedef __attribute__((ext_vector_type(8))) short bf16x8;
typedef __attribute__((ext_vector_type(4))) float f32x4;

__device__ inline unsigned short f2bf(float x) {
    unsigned int u = __float_as_uint(x);
    unsigned int r = (u + 0x7fffu + ((u >> 16) & 1u)) >> 16;
    return (unsigned short)r;
}
__device__ inline float bf2f(unsigned short h) {
    return __uint_as_float(((unsigned int)h) << 16);
}

// ---- zero ring pixels (all 256 ch) of a pixel-major [130*130][256] buffer --
__global__ __launch_bounds__(256) void zero_ringP_k(unsigned short* __restrict__ base) {
    int t = blockIdx.x * 256 + threadIdx.x;
    if (t >= 520 * 32) return;
    int ck = (t & 31) << 3, rp = t >> 5;
    int row, col;
    if (rp < 130)      { row = 0;   col = rp; }
    else if (rp < 260) { row = 129; col = rp - 130; }
    else {
        int rem = rp - 260;
        if (rem >= 256) return;            // rows 1..128 only
        row = 1 + (rem >> 1); col = (rem & 1) ? 129 : 0;
    }
    bf16x8 z = (bf16x8){0, 0, 0, 0, 0, 0, 0, 0};
    *(bf16x8*)(base + (size_t)(row * 130 + col) * 256 + ck) = z;
}

// ---- zero ccT ring pixels for channels 256..511 (Cf) -----------------------
__global__ __launch_bounds__(256) void ringT_k(unsigned short* __restrict__ ccT) {
    int t = blockIdx.x * 256 + threadIdx.x;
    if (t >= 520 * 256) return;
    int ci = t & 255, rp = t >> 8;
    int row, col;
    if (rp < 130)      { row = 0;   col = rp; }
    else if (rp < 260) { row = 129; col = rp - 130; }
    else {
        int rem = rp - 260;
        if (rem >= 256) return;            // rows 1..128 only (no OOB spill)
        row = 1 + (rem >> 1); col = (rem & 1) ? 129 : 0;
    }
    ccT[(size_t)(row * 130 + col) * 512 + 256 + ci] = 0;
}

// ---- x (256,32,32) f32 plane-major -> xT [1024][256] f32 (tiny, 1MB) -------
__global__ __launch_bounds__(256) void xT_k(const float* __restrict__ x,
                                            float* __restrict__ xT) {
    int t = blockIdx.x * 256 + threadIdx.x;    // 262,144
    int c = t & 255, pos = t >> 8;
    xT[t] = x[(size_t)c * 1024 + pos];
}

// ---- fused bilinear upsample + transpose-cvt: xT -> ccT ch 0..255 ----------
__global__ __launch_bounds__(256) void up_cvtT_k(const float* __restrict__ xT,
                                                 unsigned short* __restrict__ ccT) {
    int pix = blockIdx.x;                      // 0..16899
    int c = threadIdx.x;
    int r = pix / 130, s = pix - r * 130;
    float val = 0.0f;
    if (r >= 1 && r <= 128 && s >= 1 && s <= 128) {
        int i = r - 1, j = s - 1;
        float yf = (float)i * (31.0f / 127.0f);
        float xf = (float)j * (31.0f / 127.0f);
        int y0 = min((int)yf, 31); int y1 = min(y0 + 1, 31);
        int x0 = min((int)xf, 31); int x1 = min(x0 + 1, 31);
        float wy = yf - (float)y0, wx = xf - (float)x0;
        float v00 = xT[(size_t)(y0 * 32 + x0) * 256 + c];
        float v01 = xT[(size_t)(y0 * 32 + x1) * 256 + c];
        float v10 = xT[(size_t)(y1 * 32 + x0) * 256 + c];
        float v11 = xT[(size_t)(y1 * 32 + x1) * 256 + c];
        float a = v00 * (1.0f - wx) + v01 * wx;
        float b = v10 * (1.0f - wx) + v11 * wx;
        val = a * (1.0f - wy) + b * wy;
    }
    ccT[(size_t)pix * 512 + c] = f2bf(val);
}

// ---- LDS-tiled transpose+cvt: f32 [256][HW] -> bf16 [HW][256] --------------
__global__ __launch_bounds__(256) void cvtT_tile_k(const float* __restrict__ src,
                                                   unsigned short* __restrict__ dst) {
    __shared__ float Ls[64][65];               // 16,640 B
    int px0 = blockIdx.x << 6;                 // 256 px-tiles
    int c0  = blockIdx.y << 6;                 // 4 ch-tiles
    int t = threadIdx.x;
    int pxl = t & 63, cq = t >> 6;             // cq 0..3
#pragma unroll
    for (int it = 0; it < 16; ++it) {
        int cl = (it << 2) + cq;
        Ls[cl][pxl] = src[(size_t)(c0 + cl) * HW + px0 + pxl];
    }
    __syncthreads();
    int c8 = (t & 7) << 3;                     // 0,8,...,56
    int pxb = t >> 3;                          // 0..31
#pragma unroll
    for (int rr = 0; rr < 2; ++rr) {
        int px = pxb + (rr << 5);
        unsigned short pk[8];
#pragma unroll
        for (int e = 0; e < 8; ++e) pk[e] = f2bf(Ls[c8 + e][px]);
        *(bf16x8*)(dst + (size_t)(px0 + px) * 256 + c0 + c8) = *(bf16x8*)pk;
    }
}

// ---- fm_w / fs_w (256x256 f32) -> bf16 -------------------------------------
__global__ __launch_bounds__(256) void w2bf_k(const float* __restrict__ a,
                                              const float* __restrict__ b,
                                              unsigned short* __restrict__ da,
                                              unsigned short* __restrict__ db) {
    int t = blockIdx.x * 256 + threadIdx.x;
    if (t >= 65536) return;
    da[t] = f2bf(a[t]);
    db[t] = f2bf(b[t]);
}

// ---- u[c,h,w] = sum_k L[c,h,k]*v[c,k,w] + L[c,h,w] (f32, k-vectorized) -----
__global__ __launch_bounds__(256) void u_matmul_k(const float* __restrict__ llf,
                                                  const float* __restrict__ v,
                                                  float* __restrict__ u) {
    int c = blockIdx.y;
    const float* L = llf + (size_t)c * HW;
    const float* V = v   + (size_t)c * HW;
    float*       U = u   + (size_t)c * HW;
    int tid = threadIdx.x;
    int ty = tid >> 4, tx = tid & 15;
    int r0 = (blockIdx.x << 6) + (ty << 2);
    int w0 = tx << 3;
    float acc[4][8] = {};
    for (int k4 = 0; k4 < 128; k4 += 4) {
        float4 a4[4];
#pragma unroll
        for (int i = 0; i < 4; ++i) a4[i] = *(const float4*)(L + (r0 + i) * 128 + k4);
#pragma unroll
        for (int e = 0; e < 4; ++e) {
            float4 b0 = *(const float4*)(V + (k4 + e) * 128 + w0);
            float4 b1 = *(const float4*)(V + (k4 + e) * 128 + w0 + 4);
            float bv[8] = {b0.x, b0.y, b0.z, b0.w, b1.x, b1.y, b1.z, b1.w};
            float ae[4] = {a4[0][e], a4[1][e], a4[2][e], a4[3][e]};
#pragma unroll
            for (int i = 0; i < 4; ++i)
#pragma unroll
                for (int j = 0; j < 8; ++j) acc[i][j] += ae[i] * bv[j];
        }
    }
#pragma unroll
    for (int i = 0; i < 4; ++i) {
#pragma unroll
        for (int j = 0; j < 8; ++j) acc[i][j] += L[(r0 + i) * 128 + w0 + j];
        *(float4*)(U + (r0 + i) * 128 + w0)     = make_float4(acc[i][0], acc[i][1], acc[i][2], acc[i][3]);
        *(float4*)(U + (r0 + i) * 128 + w0 + 4) = make_float4(acc[i][4], acc[i][5], acc[i][6], acc[i][7]);
    }
}

// ---- dc_w (256,512,3,3) f32 -> wave-slice fragment-major bf16 --------------
__global__ __launch_bounds__(256) void tr_dcwF9_k(const float* __restrict__ w,
                                                  unsigned short* __restrict__ dst) {
    int t = blockIdx.x * 256 + threadIdx.x;
    if (t >= 1179648) return;                 // 72*8*2*2*64*8
    int e    = t & 7;
    int lane = (t >> 3) & 63;
    int f    = t >> 9;                        // frag index
    int mi   = f & 1;
    int s    = (f >> 1) & 1;
    int wv   = (f >> 2) & 7;
    int ch   = f >> 5;                        // chunk 0..71
    int kt   = ch >> 3;
    int o = (wv << 5) + (mi << 4) + (lane & 15);
    int c = ((ch & 7) << 6) + (s << 5) + ((lane >> 4) << 3) + e;
    dst[t] = f2bf(w[(size_t)o * 4608 + c * 9 + kt]);
}

// ---- lc weights (256,256,3,3) f32 -> fragment-major bf16 (both in one) -----
__global__ __launch_bounds__(256) void tr_lcF2_k(const float* __restrict__ w1,
                                                 const float* __restrict__ w2,
                                                 unsigned short* __restrict__ d1,
                                                 unsigned short* __restrict__ d2) {
    const float* w = blockIdx.y ? w2 : w1;
    unsigned short* dst = blockIdx.y ? d2 : d1;
    int t = blockIdx.x * 256 + threadIdx.x;
    if (t >= 589824) return;                  // 9*4*8*4*64*8
    int e    = t & 7;
    int lane = (t >> 3) & 63;
    int mi   = (t >> 9) & 3;
    int kss  = (t >> 11) & 7;
    int wo   = (t >> 14) & 3;
    int kt   = t >> 16;
    int o = (wo << 6) + (mi << 4) + (lane & 15);
    int c = (kss << 5) + ((lane >> 4) << 3) + e;
    dst[t] = f2bf(w[(size_t)o * 2304 + c * 9 + kt]);
}

// ---- p_w (18,512,3,3) f32 -> [k][32][512] bf16, zero-padded to 32 o --------
__global__ __launch_bounds__(256) void tr_pw_k(const float* __restrict__ w,
                                               unsigned short* __restrict__ dst) {
    int t = blockIdx.x * 256 + threadIdx.x;
    if (t >= 9 * 32 * 512) return;
    int c = t & 511; int rest = t >> 9; int o = rest & 31; int k = rest >> 5;
    dst[t] = (o < 18) ? f2bf(w[(size_t)o * 4608 + c * 9 + k]) : (unsigned short)0;
}

// ============ 1x1 GEMM v2: stage-once 32px x 256ch, 1 barrier, + sigmoid ====
__global__ __launch_bounds__(256, 2) void vmfma2_k(
        const unsigned short* __restrict__ inT,   // [HW][256] bf16
        const unsigned short* __restrict__ wh,    // [256][256] bf16
        float* __restrict__ vout) {               // [256][HW] f32
    __shared__ __align__(16) unsigned short Bs[32][264];     // 16,896 B
    int b = blockIdx.x;
    int xcd = b & 7, sl = b >> 3;
    int nt = (xcd << 6) + sl;
    int hrow = nt >> 2, pc0 = (nt & 3) << 5;
    int tid = threadIdx.x;
    int wv = tid >> 6, lane = tid & 63;
    int lr = lane & 15, lg = lane >> 4;
    int pbase = (hrow << 7) + pc0;
    // stage 32px x 256ch once (coalesced 512B/px rows)
#pragma unroll
    for (int ps = 0; ps < 4; ++ps) {
        int idx = ps * 2048 + tid * 8;
        int px = idx >> 8, ch = idx & 255;
        *(bf16x8*)&Bs[px][ch] = *(const bf16x8*)(inT + (size_t)(pbase + px) * 256 + ch);
    }
    __syncthreads();
    f32x4 acc[4][2];
#pragma unroll
    for (int i = 0; i < 4; ++i)
#pragma unroll
        for (int j = 0; j < 2; ++j) acc[i][j] = (f32x4){0.f, 0.f, 0.f, 0.f};
#pragma unroll
    for (int kss = 0; kss < 8; ++kss) {
        int ks = kss << 5;
        bf16x8 af[4], bfr[2];
#pragma unroll
        for (int mi = 0; mi < 4; ++mi)
            af[mi] = *(const bf16x8*)(wh + (size_t)((wv << 6) + (mi << 4) + lr) * 256 + ks + (lg << 3));
#pragma unroll
        for (int ni = 0; ni < 2; ++ni)
            bfr[ni] = *(const bf16x8*)(&Bs[(ni << 4) + lr][ks + (lg << 3)]);
#pragma unroll
        for (int mi = 0; mi < 4; ++mi)
#pragma unroll
            for (int ni = 0; ni < 2; ++ni)
                acc[mi][ni] = __builtin_amdgcn_mfma_f32_16x16x32_bf16(
                    af[mi], bfr[ni], acc[mi][ni], 0, 0, 0);
    }
#pragma unroll
    for (int mi = 0; mi < 4; ++mi)
#pragma unroll
        for (int ni = 0; ni < 2; ++ni)
#pragma unroll
            for (int r = 0; r < 4; ++r) {
                int o   = (wv << 6) + (mi << 4) + (lg << 2) + r;
                int pxx = pc0 + (ni << 4) + lr;
                vout[(size_t)o * HW + (hrow << 7) + pxx] =
                    1.0f / (1.0f + expf(-acc[mi][ni][r]));
            }
}

// ============ 1x1 GEMM v2: Cf -> ccT channels 256..511, stage-once ==========
__global__ __launch_bounds__(256, 2) void cfmfma2_k(
        const unsigned short* __restrict__ inT,   // uT [HW][256] bf16
        const unsigned short* __restrict__ wh,    // fs_w [256][256] bf16
        unsigned short* __restrict__ ccT) {       // [130*130][512] bf16
    __shared__ __align__(16) unsigned short Bs[32][264];     // 16,896 B
    int b = blockIdx.x;
    int xcd = b & 7, sl = b >> 3;
    int nt = (xcd << 6) + sl;
    int hrow = nt >> 2, pc0 = (nt & 3) << 5;
    int tid = threadIdx.x;
    int wv = tid >> 6, lane = tid & 63;
    int lr = lane & 15, lg = lane >> 4;
    int pbase = (hrow << 7) + pc0;
#pragma unroll
    for (int ps = 0; ps < 4; ++ps) {
        int idx = ps * 2048 + tid * 8;
        int px = idx >> 8, ch = idx & 255;
        *(bf16x8*)&Bs[px][ch] = *(const bf16x8*)(inT + (size_t)(pbase + px) * 256 + ch);
    }
    __syncthreads();
    f32x4 acc[4][2];
#pragma unroll
    for (int i = 0; i < 4; ++i)
#pragma unroll
        for (int j = 0; j < 2; ++j) acc[i][j] = (f32x4){0.f, 0.f, 0.f, 0.f};
#pragma unroll
    for (int kss = 0; kss < 8; ++kss) {
        int ks = kss << 5;
        bf16x8 af[4], bfr[2];
#pragma unroll
        for (int mi = 0; mi < 4; ++mi)
            af[mi] = *(const bf16x8*)(wh + (size_t)((wv << 6) + (mi << 4) + lr) * 256 + ks + (lg << 3));
#pragma unroll
        for (int ni = 0; ni < 2; ++ni)
            bfr[ni] = *(const bf16x8*)(&Bs[(ni << 4) + lr][ks + (lg << 3)]);
#pragma unroll
        for (int mi = 0; mi < 4; ++mi)
#pragma unroll
            for (int ni = 0; ni < 2; ++ni)
                acc[mi][ni] = __builtin_amdgcn_mfma_f32_16x16x32_bf16(
                    af[mi], bfr[ni], acc[mi][ni], 0, 0, 0);
    }
#pragma unroll
    for (int mi = 0; mi < 4; ++mi)
#pragma unroll
        for (int ni = 0; ni < 2; ++ni) {
            int pxx = pc0 + (ni << 4) + lr;
            int pix = (hrow + 1) * 130 + pxx + 1;
            unsigned short pk[4];
#pragma unroll
            for (int r = 0; r < 4; ++r) pk[r] = f2bf(acc[mi][ni][r]);
            *(ushort4*)(ccT + (size_t)pix * 512 + 256 + (wv << 6) + (mi << 4) + (lg << 2))
                = *(ushort4*)pk;
        }
}

// ============ offset conv 512->18 v2: stage-once halo, 1 barrier ============
__global__ __launch_bounds__(256, 2) void off_part2_k(
        const unsigned short* __restrict__ ccT,   // [130*130][512] bf16
        const unsigned short* __restrict__ pwTh,  // [9][32][512] bf16
        float* __restrict__ pbuf) {               // [4][32][HW] f32
    __shared__ __align__(16) unsigned short Ls[198][132];   // 52,272 B
    int b = blockIdx.x;                   // 1024 blocks
    int xcd = b & 7, slot = b >> 3;       // 128 slots/XCD
    int hrow = (xcd << 4) + (slot >> 3);  // XCD owns 16 contiguous hrows
    int rest = slot & 7;
    int pxh = rest >> 2, cg = rest & 3;
    int pc0h = pxh << 6, c0 = cg << 7;
    int tid = threadIdx.x;
    int wv = tid >> 6, lane = tid & 63;
    int lr = lane & 15, lg = lane >> 4;
    int wo = wv & 1;                      // o-tile (16 o of 32)
    int pt0 = (wv >> 1) << 1;             // first of 2 px-tiles for this wave
    int chk = tid & 15, pxi0 = tid >> 4;
#pragma unroll
    for (int r = 0; r < 3; ++r) {
        const unsigned short* src = ccT + (size_t)((hrow + r) * 130 + pc0h) * 512 + c0;
        for (int pxi = pxi0; pxi < 66; pxi += 16)
            *(bf16x8*)&Ls[r * 66 + pxi][chk << 3] =
                *(const bf16x8*)(src + (size_t)pxi * 512 + (chk << 3));
    }
    __syncthreads();

    f32x4 acc[2];
    acc[0] = (f32x4){0.f, 0.f, 0.f, 0.f};
    acc[1] = (f32x4){0.f, 0.f, 0.f, 0.f};
    for (int kt = 0; kt < 9; ++kt) {
        int rowb = (kt / 3) * 66 + (kt % 3);
        const unsigned short* wk = pwTh + (size_t)kt * 16384
                                 + (size_t)((wo << 4) + lr) * 512 + c0;
#pragma unroll
        for (int ks = 0; ks < 128; ks += 32) {
            bf16x8 af = *(const bf16x8*)(wk + ks + (lg << 3));
#pragma unroll
            for (int pi = 0; pi < 2; ++pi) {
                int px = ((pt0 + pi) << 4) + lr;
                bf16x8 bfr = *(const bf16x8*)(&Ls[rowb + px][ks + (lg << 3)]);
                acc[pi] = __builtin_amdgcn_mfma_f32_16x16x32_bf16(af, bfr, acc[pi], 0, 0, 0);
            }
        }
    }
#pragma unroll
    for (int pi = 0; pi < 2; ++pi)
#pragma unroll
        for (int r = 0; r < 4; ++r) {
            int o = (wo << 4) + (lg << 2) + r;
            int p = (hrow << 7) + pc0h + ((pt0 + pi) << 4) + lr;
            pbuf[(size_t)((cg << 5) + o) * HW + p] = acc[pi][r];
        }
}

// ---- per-(pixel,k): sum 4 partials; IDX = pixel-index*512 into ccT ---------
__global__ __launch_bounds__(256) void make_idx_k(const float* __restrict__ pbuf,
                                                  const float* __restrict__ pb,
                                                  int4* __restrict__ IDX,
                                                  float4* __restrict__ WT) {
    int t = blockIdx.x * 256 + threadIdx.x;
    if (t >= 9 * HW) return;
    int k = t >> 14, p = t & 16383;
    int h = p >> 7, w = p & 127;
    float ox = 0.f, oy = 0.f;
#pragma unroll
    for (int cg = 0; cg < 4; ++cg) {
        ox += pbuf[(size_t)((cg << 5) + k) * HW + p];
        oy += pbuf[(size_t)((cg << 5) + 9 + k) * HW + p];
    }
    float px = ox + pb[k]     + (float)(k / 3 - 1) + (float)(h + 1);
    float py = oy + pb[9 + k] + (float)(k % 3 - 1) + (float)(w + 1);
    float fx = floorf(px), fy = floorf(py);
    float x0 = fminf(fmaxf(fx,        0.f), 129.f);
    float x1 = fminf(fmaxf(fx + 1.0f, 0.f), 129.f);
    float y0 = fminf(fmaxf(fy,        0.f), 129.f);
    float y1 = fminf(fmaxf(fy + 1.0f, 0.f), 129.f);
    float pxc = fminf(fmaxf(px, 0.f), 129.f);
    float pyc = fminf(fmaxf(py, 0.f), 129.f);
    float gx0 = 1.0f + x0 - pxc, gx1 = 1.0f - x1 + pxc;
    float gy0 = 1.0f + y0 - pyc, gy1 = 1.0f - y1 + pyc;
    int ix0 = (int)x0, ix1 = (int)x1, iy0 = (int)y0, iy1 = (int)y1;
    IDX[t] = make_int4((ix0 * 130 + iy0) << 9, (ix1 * 130 + iy1) << 9,
                       (ix0 * 130 + iy1) << 9, (ix1 * 130 + iy0) << 9);
    WT[t]  = make_float4(gx0 * gy0, gx1 * gy1, gx0 * gy1, gx1 * gy0);
}

// ============ deformable contraction v10 (FROZEN at fam9, 74us) =============
__global__ __launch_bounds__(512, 4) void fam9_k(
        const unsigned short* __restrict__ ccT,    // [130*130][512] bf16
        const unsigned short* __restrict__ dcwF,   // [72][8][2][2][64][8] bf16
        const int4* __restrict__ IDX, const float4* __restrict__ WT,
        unsigned short* __restrict__ part0,        // [HW][256] bf16
        unsigned short* __restrict__ part1) {      // [HW][256] bf16
    __shared__ __align__(16) unsigned short Bs[2][64][72];   // 18,432 B
    int b = blockIdx.x;                 // 512 blocks
    int khalf = b >> 8;                 // K-half: chunks [0,36) or [36,72)
    int bb = b & 255;
    int xcd = bb & 7, sl = bb >> 3;     // 32 slots per XCD
    int nt = (xcd << 5) + sl;           // XCD owns 16 contiguous hrows
    int hrow = nt >> 1, pc0 = (nt & 1) << 6;
    int tid = threadIdx.x;
    int wv = tid >> 6, lane = tid & 63;
    int lr = lane & 15, lg = lane >> 4;
    int pxg = tid >> 3, grp = tid & 7;  // gather: 64 px x 8 ch-groups of 16B
    int p2 = (hrow << 7) + pc0 + pxg;   // this thread's gather pixel
    const unsigned short* wfb = dcwF + ((size_t)wv << 11) + ((size_t)lane << 3);
    f32x4 acc[2][4];
#pragma unroll
    for (int i = 0; i < 2; ++i)
#pragma unroll
        for (int j = 0; j < 4; ++j) acc[i][j] = (f32x4){0.f, 0.f, 0.f, 0.f};

    bf16x8 v0, v1, v2, v3;              // gather regs (single set)
    bf16x8 Aa00, Aa01, Aa10, Aa11;      // A-frag set A (even chunks)
    bf16x8 Ba00, Ba01, Ba10, Ba11;      // A-frag set B (odd chunks)

#define ISSUE_A9(S, ch) do {                                                  \
    const unsigned short* ap_ = wfb + ((size_t)(ch) << 14);                   \
    S##00 = *(const bf16x8*)(ap_);                                            \
    S##01 = *(const bf16x8*)(ap_ + 512);                                      \
    S##10 = *(const bf16x8*)(ap_ + 1024);                                     \
    S##11 = *(const bf16x8*)(ap_ + 1536);                                     \
} while (0)

#define ISSUE_G9(ch, idm) do {                                                \
    int cb_ = (((ch) & 7) << 6) + (grp << 3);                                 \
    v0 = *(const bf16x8*)(ccT + (idm).x + cb_);                               \
    v1 = *(const bf16x8*)(ccT + (idm).y + cb_);                               \
    v2 = *(const bf16x8*)(ccT + (idm).z + cb_);                               \
    v3 = *(const bf16x8*)(ccT + (idm).w + cb_);                               \
} while (0)

#define NEXT_G9(cn) do {                                                      \
    if ((cn) < c1) {                                                          \
        if (((cn) & 7) == 0) {                                                \
            idc = idn; wtc = wtn;                                             \
            int kt2_ = ((cn) >> 3) + 1;                                       \
            if ((kt2_ << 3) < c1) {                                           \
                idn = IDX[(kt2_ << 14) + p2];                                 \
                wtn = WT [(kt2_ << 14) + p2];                                 \
            }                                                                 \
        }                                                                     \
        ISSUE_G9(cn, idc);                                                    \
        wnext = wtc;                                                          \
    }                                                                         \
} while (0)

#define PUBLISH9(bi) do {                                                     \
    unsigned short pk_[8];                                                    \
    _Pragma("unroll")                                                         \
    for (int e_ = 0; e_ < 8; ++e_) {                                          \
        float val_ = wcur.x * bf2f((unsigned short)v0[e_])                    \
                   + wcur.y * bf2f((unsigned short)v1[e_])                    \
                   + wcur.z * bf2f((unsigned short)v2[e_])                    \
                   + wcur.w * bf2f((unsigned short)v3[e_]);                   \
        pk_[e_] = f2bf(val_);                                                 \
    }                                                                         \
    *(bf16x8*)&Bs[bi][pxg][grp << 3] = *(bf16x8*)pk_;                         \
} while (0)

#define MFMA9(S, bi) do {                                                     \
    _Pragma("unroll")                                                         \
    for (int ni_ = 0; ni_ < 4; ++ni_) {                                       \
        bf16x8 b0_ = *(const bf16x8*)(&Bs[bi][(ni_ << 4) + lr][lg << 3]);     \
        acc[0][ni_] = __builtin_amdgcn_mfma_f32_16x16x32_bf16(S##00, b0_, acc[0][ni_], 0, 0, 0); \
        acc[1][ni_] = __builtin_amdgcn_mfma_f32_16x16x32_bf16(S##01, b0_, acc[1][ni_], 0, 0, 0); \
    }                                                                         \
    _Pragma("unroll")                                                         \
    for (int ni_ = 0; ni_ < 4; ++ni_) {                                       \
        bf16x8 b1_ = *(const bf16x8*)(&Bs[bi][(ni_ << 4) + lr][32 + (lg << 3)]); \
        acc[0][ni_] = __builtin_amdgcn_mfma_f32_16x16x32_bf16(S##10, b1_, acc[0][ni_], 0, 0, 0); \
        acc[1][ni_] = __builtin_amdgcn_mfma_f32_16x16x32_bf16(S##11, b1_, acc[1][ni_], 0, 0, 0); \
    }                                                                         \
} while (0)

    int c0 = khalf * 36, c1 = c0 + 36;
    int kt0 = c0 >> 3;
    int4   idc = IDX[(kt0 << 14) + p2];
    float4 wtc = WT [(kt0 << 14) + p2];
    int4   idn = IDX[((kt0 + 1) << 14) + p2];
    float4 wtn = WT [((kt0 + 1) << 14) + p2];
    ISSUE_G9(c0, idc);
    float4 wcur = wtc, wnext = wtc;
    ISSUE_A9(Aa, c0);

    for (int c = c0; c < c1; c += 2) {
        // even chunk c -> Bs[0], consumes Aa
        PUBLISH9(0);                    // weighting of gather(c)
        NEXT_G9(c + 1);                 // gather(c+1) in flight across MFMA(c)
        ISSUE_A9(Ba, c + 1);            // A(c+1) in flight across MFMA(c)
        __syncthreads();                // publish(c) visible; MFMA(c-1) done
        MFMA9(Aa, 0);
        wcur = wnext;
        // odd chunk c+1 -> Bs[1], consumes Ba
        PUBLISH9(1);
        NEXT_G9(c + 2);
        if (c + 2 < c1) ISSUE_A9(Aa, c + 2);
        __syncthreads();
        MFMA9(Ba, 1);
        wcur = wnext;
    }
#undef ISSUE_A9
#undef ISSUE_G9
#undef NEXT_G9
#undef PUBLISH9
#undef MFMA9

    unsigned short* pt = khalf ? part1 : part0;
#pragma unroll
    for (int mi = 0; mi < 2; ++mi)
#pragma unroll
        for (int ni = 0; ni < 4; ++ni) {
            int pxx = pc0 + (ni << 4) + lr;
            int p = (hrow << 7) + pxx;
            unsigned short pk[4];
#pragma unroll
            for (int r = 0; r < 4; ++r) pk[r] = f2bf(acc[mi][ni][r]);
            *(ushort4*)(pt + (size_t)p * 256 + (wv << 5) + (mi << 4) + (lg << 2))
                = *(ushort4*)pk;
        }
}

// ============ 3x3 conv #1: staging FUSES part0+part1+Cf combine =============
// Replaces combineT + famT round-trip (45MB traffic + 1 launch): the sum is
// computed during the halo staging (same f2bf math, bit-identical values);
// ring positions stage 0.
__global__ __launch_bounds__(256, 2) void conv2c_k(
        const unsigned short* __restrict__ p0,    // [HW][256] bf16
        const unsigned short* __restrict__ p1,    // [HW][256] bf16
        const unsigned short* __restrict__ ccT,   // [130*130][512], Cf at +256
        const unsigned short* __restrict__ wF,    // frag-major [9][4][8][4][64][8]
        const float* __restrict__ gam, const float* __restrict__ bet,
        const float* __restrict__ mean, const float* __restrict__ var,
        float* __restrict__ out_flat,             // [256][HW] f32
        unsigned short* __restrict__ out_padT) {  // [130*130][256]
    __shared__ __align__(16) unsigned short Ls[102][264];   // 53,856 B
    __shared__ float scs[256], bis[256];
    int b = blockIdx.x;
    int xcd = b & 7, slot = b >> 3;
    int nt = (xcd << 6) + slot;
    int hrow = nt >> 2, pc0 = (nt & 3) << 5;
    int tid = threadIdx.x;
    int wv = tid >> 6, lane = tid & 63;
    int lr = lane & 15, lg = lane >> 4;
    {
        float sc = gam[tid] * rsqrtf(var[tid] + 1e-5f);
        scs[tid] = sc;
        bis[tid] = bet[tid] - mean[tid] * sc;
    }
#pragma unroll
    for (int r = 0; r < 3; ++r) {
        int rr = hrow + r;                        // 0..129
#pragma unroll
        for (int ps = 0; ps < 5; ++ps) {
            int idx = ps * 2048 + tid * 8;
            if (idx < 8704) {                     // 34*256
                int pxi = idx >> 8, ch = idx & 255;
                int cc = pc0 + pxi;               // 0..129
                bf16x8 v = (bf16x8){0, 0, 0, 0, 0, 0, 0, 0};
                if (rr >= 1 && rr <= 128 && cc >= 1 && cc <= 128) {
                    int p = ((rr - 1) << 7) + (cc - 1);
                    bf16x8 a  = *(const bf16x8*)(p0 + (size_t)p * 256 + ch);
                    bf16x8 bb = *(const bf16x8*)(p1 + (size_t)p * 256 + ch);
                    bf16x8 cf = *(const bf16x8*)(ccT + (size_t)(rr * 130 + cc) * 512 + 256 + ch);
                    unsigned short pk[8];
#pragma unroll
                    for (int e = 0; e < 8; ++e)
                        pk[e] = f2bf(bf2f((unsigned short)a[e]) + bf2f((unsigned short)bb[e])
                                     + bf2f((unsigned short)cf[e]));
                    v = *(bf16x8*)pk;
                }
                *(bf16x8*)&Ls[r * 34 + pxi][ch] = v;
            }
        }
    }
    __syncthreads();

    f32x4 acc[4][2];
#pragma unroll
    for (int i = 0; i < 4; ++i)
#pragma unroll
        for (int j = 0; j < 2; ++j) acc[i][j] = (f32x4){0.f, 0.f, 0.f, 0.f};

    const unsigned short* wvb = wF + ((size_t)wv << 14) + ((size_t)lane << 3);
    for (int kt = 0; kt < 9; ++kt) {
        int rowb = (kt / 3) * 34 + (kt % 3);
        const unsigned short* wkb = wvb + (size_t)kt * 65536;
#pragma unroll
        for (int kss = 0; kss < 8; ++kss) {
            int ks = kss << 5;
            bf16x8 af[4], bfr[2];
#pragma unroll
            for (int mi = 0; mi < 4; ++mi)
                af[mi] = *(const bf16x8*)(wkb + (size_t)kss * 2048 + mi * 512);
#pragma unroll
            for (int ni = 0; ni < 2; ++ni)
                bfr[ni] = *(const bf16x8*)(&Ls[rowb + (ni << 4) + lr][ks + (lg << 3)]);
#pragma unroll
            for (int mi = 0; mi < 4; ++mi)
#pragma unroll
                for (int ni = 0; ni < 2; ++ni)
                    acc[mi][ni] = __builtin_amdgcn_mfma_f32_16x16x32_bf16(
                        af[mi], bfr[ni], acc[mi][ni], 0, 0, 0);
        }
    }

#pragma unroll
    for (int mi = 0; mi < 4; ++mi)
#pragma unroll
        for (int ni = 0; ni < 2; ++ni) {
            int pxx = pc0 + (ni << 4) + lr;
            unsigned short pk[4];
#pragma unroll
            for (int r = 0; r < 4; ++r) {
                int o = (wv << 6) + (mi << 4) + (lg << 2) + r;
                float rv = fmaxf(acc[mi][ni][r] * scs[o] + bis[o], 0.0f);
                out_flat[(size_t)o * HW + (hrow << 7) + pxx] = rv;
                pk[r] = f2bf(rv);
            }
            int pix = (hrow + 1) * 130 + pxx + 1;
            *(ushort4*)(out_padT + (size_t)pix * 256 + (wv << 6) + (mi << 4) + (lg << 2))
                = *(ushort4*)pk;
        }
}

// ============ 3x3 conv #2: stage-once pixel-major, 1 barrier ================
__global__ __launch_bounds__(256, 2) void conv2T_k(
        const unsigned short* __restrict__ inT,   // [130*130][256] bf16, ring=0
        const unsigned short* __restrict__ wF,    // frag-major [9][4][8][4][64][8]
        const float* __restrict__ gam, const float* __restrict__ bet,
        const float* __restrict__ mean, const float* __restrict__ var,
        float* __restrict__ out_flat) {           // [256][HW] f32
    __shared__ __align__(16) unsigned short Ls[102][264];   // 53,856 B
    __shared__ float scs[256], bis[256];
    int b = blockIdx.x;
    int xcd = b & 7, slot = b >> 3;
    int nt = (xcd << 6) + slot;
    int hrow = nt >> 2, pc0 = (nt & 3) << 5;
    int tid = threadIdx.x;
    int wv = tid >> 6, lane = tid & 63;
    int lr = lane & 15, lg = lane >> 4;
    {
        float sc = gam[tid] * rsqrtf(var[tid] + 1e-5f);
        scs[tid] = sc;
        bis[tid] = bet[tid] - mean[tid] * sc;
    }
#pragma unroll
    for (int r = 0; r < 3; ++r) {
        const unsigned short* src = inT + (size_t)((hrow + r) * 130 + pc0) * 256;
#pragma unroll
        for (int ps = 0; ps < 5; ++ps) {
            int idx = ps * 2048 + tid * 8;
            if (idx < 8704) {                     // 34*256
                bf16x8 v = *(const bf16x8*)(src + idx);
                *(bf16x8*)&Ls[r * 34 + (idx >> 8)][idx & 255] = v;
            }
        }
    }
    __syncthreads();

    f32x4 acc[4][2];
#pragma unroll
    for (int i = 0; i < 4; ++i)
#pragma unroll
        for (int j = 0; j < 2; ++j) acc[i][j] = (f32x4){0.f, 0.f, 0.f, 0.f};

    const unsigned short* wvb = wF + ((size_t)wv << 14) + ((size_t)lane << 3);
    for (int kt = 0; kt < 9; ++kt) {
        int rowb = (kt / 3) * 34 + (kt % 3);
        const unsigned short* wkb = wvb + (size_t)kt * 65536;
#pragma unroll
        for (int kss = 0; kss < 8; ++kss) {
            int ks = kss << 5;
            bf16x8 af[4], bfr[2];
#pragma unroll
            for (int mi = 0; mi < 4; ++mi)
                af[mi] = *(const bf16x8*)(wkb + (size_t)kss * 2048 + mi * 512);
#pragma unroll
            for (int ni = 0; ni < 2; ++ni)
                bfr[ni] = *(const bf16x8*)(&Ls[rowb + (ni << 4) + lr][ks + (lg << 3)]);
#pragma unroll
            for (int mi = 0; mi < 4; ++mi)
#pragma unroll
                for (int ni = 0; ni < 2; ++ni)
                    acc[mi][ni] = __builtin_amdgcn_mfma_f32_16x16x32_bf16(
                        af[mi], bfr[ni], acc[mi][ni], 0, 0, 0);
        }
    }

#pragma unroll
    for (int mi = 0; mi < 4; ++mi)
#pragma unroll
        for (int ni = 0; ni < 2; ++ni) {
            int pxx = pc0 + (ni << 4) + lr;
#pragma unroll
            for (int r = 0; r < 4; ++r) {
                int o = (wv << 6) + (mi << 4) + (lg << 2) + r;
                float rv = fmaxf(acc[mi][ni][r] * scs[o] + bis[o], 0.0f);
                out_flat[(size_t)o * HW + (hrow << 7) + pxx] = rv;
            }
        }
}

extern "C" void kernel_launch(void* const* d_in, const int* in_sizes, int n_in,
                              void* d_out, int out_size, void* d_ws, size_t ws_size,
                              hipStream_t stream) {
    const float* x     = (const float*)d_in[0];
    const float* llf   = (const float*)d_in[1];
    const float* fm_w  = (const float*)d_in[2];
    const float* fs_w  = (const float*)d_in[3];
    const float* p_w   = (const float*)d_in[4];
    const float* p_b   = (const float*)d_in[5];
    const float* dc_w  = (const float*)d_in[6];
    const float* lc1_w = (const float*)d_in[7];
    const float* bn1g  = (const float*)d_in[8];
    const float* bn1b  = (const float*)d_in[9];
    const float* bn1m  = (const float*)d_in[10];
    const float* bn1v  = (const float*)d_in[11];
    const float* lc2_w = (const float*)d_in[12];
    const float* bn2g  = (const float*)d_in[13];
    const float* bn2b  = (const float*)d_in[14];
    const float* bn2m  = (const float*)d_in[15];
    const float* bn2v  = (const float*)d_in[16];
    float* out1 = (float*)d_out;
    float* out2 = out1 + (size_t)256 * HW;

    // d_out is WRITE-ONLY (pure outputs). All scratch lives in ws.
    if (ws_size < 79839232u) return;
    char* ws = (char*)d_ws;
    unsigned short* ccT   = (unsigned short*)ws;                // [0, 17,305,600)
    float*          xTf   = (float*)(ws + 17305600);            // 1MB, dead after up_cvtT
    float*          vbuf  = (float*)(ws + 17305600);
    unsigned short* up1T  = (unsigned short*)(ws + 26091520);   // [130*130][256]
    unsigned short* llfT  = (unsigned short*)(ws + 34877440);   // dead after vmfma
    unsigned short* uT    = (unsigned short*)(ws + 43266048);   // dead after cfmfma
    unsigned short* part0 = (unsigned short*)(ws + 43266048);   // fam9 partial khalf=0
    unsigned short* fmwh  = (unsigned short*)(ws + 51654656);   // 131,072
    unsigned short* fswh  = (unsigned short*)(ws + 51785728);   // 131,072
    float*          ubuf  = (float*)(ws + 51916800);            // U region
    float*          pbuf  = (float*)(ws + 51916800);            // dead after make_idx
    unsigned short* part1 = (unsigned short*)(ws + 51916800);   // fam9 partial khalf=1
    int4*           IDX   = (int4*)  (ws + 60305408);
    float4*         WT    = (float4*)(ws + 62664704);
    unsigned short* dcwF   = (unsigned short*)(ws + 68694016);  // 2,359,296 (frag-major)
    unsigned short* lcw1F  = (unsigned short*)(ws + 71053312);  // 1,179,648
    unsigned short* lcw2F  = (unsigned short*)(ws + 72232960);  // 1,179,648
    unsigned short* pwTh   = (unsigned short*)(ws + 73412608);  //   294,912

    xT_k<<<dim3(1024), 256, 0, stream>>>(x, xTf);
    up_cvtT_k<<<dim3(16900), 256, 0, stream>>>(xTf, ccT);         // ccT ch 0..255 (+ring0)
    cvtT_tile_k<<<dim3(256, 4), 256, 0, stream>>>(llf, llfT);
    w2bf_k<<<dim3(256), 256, 0, stream>>>(fm_w, fs_w, fmwh, fswh);
    vmfma2_k<<<dim3(512), 256, 0, stream>>>(llfT, fmwh, vbuf);    // llfT dead after
    u_matmul_k<<<dim3(2, 256), 256, 0, stream>>>(llf, vbuf, ubuf);  // vbuf dead after
    cvtT_tile_k<<<dim3(256, 4), 256, 0, stream>>>(ubuf, uT);      // ubuf dead after
    tr_dcwF9_k<<<dim3(4608), 256, 0, stream>>>(dc_w, dcwF);       // wave-slice frag-major
    tr_lcF2_k<<<dim3(2304, 2), 256, 0, stream>>>(lc1_w, lc2_w, lcw1F, lcw2F);
    tr_pw_k<<<dim3(576), 256, 0, stream>>>(p_w, pwTh);
    cfmfma2_k<<<dim3(512), 256, 0, stream>>>(uT, fswh, ccT);      // uT dead after
    ringT_k<<<dim3(520), 256, 0, stream>>>(ccT);                  // Cf ring = 0
    off_part2_k<<<dim3(1024), 256, 0, stream>>>(ccT, pwTh, pbuf);
    make_idx_k<<<dim3(576), 256, 0, stream>>>(pbuf, p_b, IDX, WT);  // pbuf dead after
    zero_ringP_k<<<dim3(65), 256, 0, stream>>>(up1T);
    fam9_k<<<dim3(512), 512, 0, stream>>>(ccT, dcwF, IDX, WT, part0, part1);
    conv2c_k<<<dim3(512), 256, 0, stream>>>(part0, part1, ccT, lcw1F,
                                            bn1g, bn1b, bn1m, bn1v, out1, up1T);
    conv2T_k<<<dim3(512), 256, 0, stream>>>(up1T, lcw2F, bn2g, bn2b, bn2m, bn2v,
                                            out2);
}

// Round 12
// 395.762 us; speedup vs baseline: 1.0367x; 1.0367x over previous
//
#include <hip/hip_runtime.h>
#include <math.h>

#define HW   16384           // 128*128
#define PS   16900           // 130*130 padded plane

typedef __attribute__((ext_vector_type(8))) short bf16x8;
typedef __attribute__((ext_vector_type(4))) float f32x4;

__device__ inline unsigned short f2bf(float x) {
    unsigned int u = __float_as_uint(x);
    unsigned int r = (u + 0x7fffu + ((u >> 16) & 1u)) >> 16;
    return (unsigned short)r;
}
__device__ inline float bf2f(unsigned short h) {
    return __uint_as_float(((unsigned int)h) << 16);
}

// ---- zero ring pixels (all 256 ch) of TWO pixel-major [130*130][256] bufs --
__global__ __launch_bounds__(256) void zero_ringP2_k(unsigned short* __restrict__ b0,
                                                     unsigned short* __restrict__ b1) {
    int t = blockIdx.x * 256 + threadIdx.x;
    if (t >= 2 * 520 * 32) return;
    unsigned short* base = (t >= 520 * 32) ? b1 : b0;
    int tt = (t >= 520 * 32) ? t - 520 * 32 : t;
    int ck = (tt & 31) << 3, rp = tt >> 5;
    int row, col;
    if (rp < 130)      { row = 0;   col = rp; }
    else if (rp < 260) { row = 129; col = rp - 130; }
    else {
        int rem = rp - 260;
        if (rem >= 256) return;            // rows 1..128 only
        row = 1 + (rem >> 1); col = (rem & 1) ? 129 : 0;
    }
    bf16x8 z = (bf16x8){0, 0, 0, 0, 0, 0, 0, 0};
    *(bf16x8*)(base + (size_t)(row * 130 + col) * 256 + ck) = z;
}

// ---- zero ccT ring pixels for channels 256..511 (Cf) -----------------------
__global__ __launch_bounds__(256) void ringT_k(unsigned short* __restrict__ ccT) {
    int t = blockIdx.x * 256 + threadIdx.x;
    if (t >= 520 * 256) return;
    int ci = t & 255, rp = t >> 8;
    int row, col;
    if (rp < 130)      { row = 0;   col = rp; }
    else if (rp < 260) { row = 129; col = rp - 130; }
    else {
        int rem = rp - 260;
        if (rem >= 256) return;            // rows 1..128 only (no OOB spill)
        row = 1 + (rem >> 1); col = (rem & 1) ? 129 : 0;
    }
    ccT[(size_t)(row * 130 + col) * 512 + 256 + ci] = 0;
}

// ---- x (256,32,32) f32 plane-major -> xT [1024][256] f32 (tiny, 1MB) -------
__global__ __launch_bounds__(256) void xT_k(const float* __restrict__ x,
                                            float* __restrict__ xT) {
    int t = blockIdx.x * 256 + threadIdx.x;    // 262,144
    int c = t & 255, pos = t >> 8;
    xT[t] = x[(size_t)c * 1024 + pos];
}

// ---- fused bilinear upsample + transpose-cvt: xT -> ccT ch 0..255 ----------
__global__ __launch_bounds__(256) void up_cvtT_k(const float* __restrict__ xT,
                                                 unsigned short* __restrict__ ccT) {
    int pix = blockIdx.x;                      // 0..16899
    int c = threadIdx.x;
    int r = pix / 130, s = pix - r * 130;
    float val = 0.0f;
    if (r >= 1 && r <= 128 && s >= 1 && s <= 128) {
        int i = r - 1, j = s - 1;
        float yf = (float)i * (31.0f / 127.0f);
        float xf = (float)j * (31.0f / 127.0f);
        int y0 = min((int)yf, 31); int y1 = min(y0 + 1, 31);
        int x0 = min((int)xf, 31); int x1 = min(x0 + 1, 31);
        float wy = yf - (float)y0, wx = xf - (float)x0;
        float v00 = xT[(size_t)(y0 * 32 + x0) * 256 + c];
        float v01 = xT[(size_t)(y0 * 32 + x1) * 256 + c];
        float v10 = xT[(size_t)(y1 * 32 + x0) * 256 + c];
        float v11 = xT[(size_t)(y1 * 32 + x1) * 256 + c];
        float a = v00 * (1.0f - wx) + v01 * wx;
        float b = v10 * (1.0f - wx) + v11 * wx;
        val = a * (1.0f - wy) + b * wy;
    }
    ccT[(size_t)pix * 512 + c] = f2bf(val);
}

// ---- LDS-tiled transpose+cvt: f32 [256][HW] -> bf16 [HW][256] --------------
__global__ __launch_bounds__(256) void cvtT_tile_k(const float* __restrict__ src,
                                                   unsigned short* __restrict__ dst) {
    __shared__ float Ls[64][65];               // 16,640 B
    int px0 = blockIdx.x << 6;                 // 256 px-tiles
    int c0  = blockIdx.y << 6;                 // 4 ch-tiles
    int t = threadIdx.x;
    int pxl = t & 63, cq = t >> 6;             // cq 0..3
#pragma unroll
    for (int it = 0; it < 16; ++it) {
        int cl = (it << 2) + cq;
        Ls[cl][pxl] = src[(size_t)(c0 + cl) * HW + px0 + pxl];
    }
    __syncthreads();
    int c8 = (t & 7) << 3;                     // 0,8,...,56
    int pxb = t >> 3;                          // 0..31
#pragma unroll
    for (int rr = 0; rr < 2; ++rr) {
        int px = pxb + (rr << 5);
        unsigned short pk[8];
#pragma unroll
        for (int e = 0; e < 8; ++e) pk[e] = f2bf(Ls[c8 + e][px]);
        *(bf16x8*)(dst + (size_t)(px0 + px) * 256 + c0 + c8) = *(bf16x8*)pk;
    }
}

// ---- fm_w / fs_w (256x256 f32) -> bf16 -------------------------------------
__global__ __launch_bounds__(256) void w2bf_k(const float* __restrict__ a,
                                              const float* __restrict__ b,
                                              unsigned short* __restrict__ da,
                                              unsigned short* __restrict__ db) {
    int t = blockIdx.x * 256 + threadIdx.x;
    if (t >= 65536) return;
    da[t] = f2bf(a[t]);
    db[t] = f2bf(b[t]);
}

// ---- u[c,h,w] = sum_k L[c,h,k]*v[c,k,w] + L[c,h,w] (f32) -------------------
__global__ __launch_bounds__(256) void u_matmul_k(const float* __restrict__ llf,
                                                  const float* __restrict__ v,
                                                  float* __restrict__ u) {
    int c = blockIdx.y;
    const float* L = llf + (size_t)c * HW;
    const float* V = v   + (size_t)c * HW;
    float*       U = u   + (size_t)c * HW;
    int tid = threadIdx.x;
    int ty = tid >> 4, tx = tid & 15;
    int r0 = (blockIdx.x << 6) + (ty << 2);
    int w0 = tx << 3;
    float acc[4][8] = {};
    for (int k = 0; k < 128; ++k) {
        float a[4];
#pragma unroll
        for (int i = 0; i < 4; ++i) a[i] = L[(r0 + i) * 128 + k];
        float4 b0 = *(const float4*)(V + k * 128 + w0);
        float4 b1 = *(const float4*)(V + k * 128 + w0 + 4);
        float bv[8] = {b0.x, b0.y, b0.z, b0.w, b1.x, b1.y, b1.z, b1.w};
#pragma unroll
        for (int i = 0; i < 4; ++i)
#pragma unroll
            for (int j = 0; j < 8; ++j) acc[i][j] += a[i] * bv[j];
    }
#pragma unroll
    for (int i = 0; i < 4; ++i) {
#pragma unroll
        for (int j = 0; j < 8; ++j) acc[i][j] += L[(r0 + i) * 128 + w0 + j];
        *(float4*)(U + (r0 + i) * 128 + w0)     = make_float4(acc[i][0], acc[i][1], acc[i][2], acc[i][3]);
        *(float4*)(U + (r0 + i) * 128 + w0 + 4) = make_float4(acc[i][4], acc[i][5], acc[i][6], acc[i][7]);
    }
}

// ---- dc_w (256,512,3,3) f32 -> wave-slice fragment-major bf16 --------------
__global__ __launch_bounds__(256) void tr_dcwF9_k(const float* __restrict__ w,
                                                  unsigned short* __restrict__ dst) {
    int t = blockIdx.x * 256 + threadIdx.x;
    if (t >= 1179648) return;                 // 72*8*2*2*64*8
    int e    = t & 7;
    int lane = (t >> 3) & 63;
    int f    = t >> 9;                        // frag index
    int mi   = f & 1;
    int s    = (f >> 1) & 1;
    int wv   = (f >> 2) & 7;
    int ch   = f >> 5;                        // chunk 0..71
    int kt   = ch >> 3;
    int o = (wv << 5) + (mi << 4) + (lane & 15);
    int c = ((ch & 7) << 6) + (s << 5) + ((lane >> 4) << 3) + e;
    dst[t] = f2bf(w[(size_t)o * 4608 + c * 9 + kt]);
}

// ---- lc weights (256,256,3,3) f32 -> fragment-major bf16 (both in one) -----
__global__ __launch_bounds__(256) void tr_lcF2_k(const float* __restrict__ w1,
                                                 const float* __restrict__ w2,
                                                 unsigned short* __restrict__ d1,
                                                 unsigned short* __restrict__ d2) {
    const float* w = blockIdx.y ? w2 : w1;
    unsigned short* dst = blockIdx.y ? d2 : d1;
    int t = blockIdx.x * 256 + threadIdx.x;
    if (t >= 589824) return;                  // 9*4*8*4*64*8
    int e    = t & 7;
    int lane = (t >> 3) & 63;
    int mi   = (t >> 9) & 3;
    int kss  = (t >> 11) & 7;
    int wo   = (t >> 14) & 3;
    int kt   = t >> 16;
    int o = (wo << 6) + (mi << 4) + (lane & 15);
    int c = (kss << 5) + ((lane >> 4) << 3) + e;
    dst[t] = f2bf(w[(size_t)o * 2304 + c * 9 + kt]);
}

// ---- p_w (18,512,3,3) f32 -> [k][32][512] bf16, zero-padded to 32 o --------
__global__ __launch_bounds__(256) void tr_pw_k(const float* __restrict__ w,
                                               unsigned short* __restrict__ dst) {
    int t = blockIdx.x * 256 + threadIdx.x;
    if (t >= 9 * 32 * 512) return;
    int c = t & 511; int rest = t >> 9; int o = rest & 31; int k = rest >> 5;
    dst[t] = (o < 18) ? f2bf(w[(size_t)o * 4608 + c * 9 + k]) : (unsigned short)0;
}

// ============ 1x1 GEMM v2: stage-once 32px x 256ch, 1 barrier, + sigmoid ====
__global__ __launch_bounds__(256, 2) void vmfma2_k(
        const unsigned short* __restrict__ inT,   // [HW][256] bf16
        const unsigned short* __restrict__ wh,    // [256][256] bf16
        float* __restrict__ vout) {               // [256][HW] f32
    __shared__ __align__(16) unsigned short Bs[32][264];     // 16,896 B
    int b = blockIdx.x;
    int xcd = b & 7, sl = b >> 3;
    int nt = (xcd << 6) + sl;
    int hrow = nt >> 2, pc0 = (nt & 3) << 5;
    int tid = threadIdx.x;
    int wv = tid >> 6, lane = tid & 63;
    int lr = lane & 15, lg = lane >> 4;
    int pbase = (hrow << 7) + pc0;
    // stage 32px x 256ch once (coalesced 512B/px rows)
#pragma unroll
    for (int ps = 0; ps < 4; ++ps) {
        int idx = ps * 2048 + tid * 8;
        int px = idx >> 8, ch = idx & 255;
        *(bf16x8*)&Bs[px][ch] = *(const bf16x8*)(inT + (size_t)(pbase + px) * 256 + ch);
    }
    __syncthreads();
    f32x4 acc[4][2];
#pragma unroll
    for (int i = 0; i < 4; ++i)
#pragma unroll
        for (int j = 0; j < 2; ++j) acc[i][j] = (f32x4){0.f, 0.f, 0.f, 0.f};
#pragma unroll
    for (int kss = 0; kss < 8; ++kss) {
        int ks = kss << 5;
        bf16x8 af[4], bfr[2];
#pragma unroll
        for (int mi = 0; mi < 4; ++mi)
            af[mi] = *(const bf16x8*)(wh + (size_t)((wv << 6) + (mi << 4) + lr) * 256 + ks + (lg << 3));
#pragma unroll
        for (int ni = 0; ni < 2; ++ni)
            bfr[ni] = *(const bf16x8*)(&Bs[(ni << 4) + lr][ks + (lg << 3)]);
#pragma unroll
        for (int mi = 0; mi < 4; ++mi)
#pragma unroll
            for (int ni = 0; ni < 2; ++ni)
                acc[mi][ni] = __builtin_amdgcn_mfma_f32_16x16x32_bf16(
                    af[mi], bfr[ni], acc[mi][ni], 0, 0, 0);
    }
#pragma unroll
    for (int mi = 0; mi < 4; ++mi)
#pragma unroll
        for (int ni = 0; ni < 2; ++ni)
#pragma unroll
            for (int r = 0; r < 4; ++r) {
                int o   = (wv << 6) + (mi << 4) + (lg << 2) + r;
                int pxx = pc0 + (ni << 4) + lr;
                vout[(size_t)o * HW + (hrow << 7) + pxx] =
                    1.0f / (1.0f + expf(-acc[mi][ni][r]));
            }
}

// ============ 1x1 GEMM v2: Cf -> ccT channels 256..511, stage-once ==========
__global__ __launch_bounds__(256, 2) void cfmfma2_k(
        const unsigned short* __restrict__ inT,   // uT [HW][256] bf16
        const unsigned short* __restrict__ wh,    // fs_w [256][256] bf16
        unsigned short* __restrict__ ccT) {       // [130*130][512] bf16
    __shared__ __align__(16) unsigned short Bs[32][264];     // 16,896 B
    int b = blockIdx.x;
    int xcd = b & 7, sl = b >> 3;
    int nt = (xcd << 6) + sl;
    int hrow = nt >> 2, pc0 = (nt & 3) << 5;
    int tid = threadIdx.x;
    int wv = tid >> 6, lane = tid & 63;
    int lr = lane & 15, lg = lane >> 4;
    int pbase = (hrow << 7) + pc0;
#pragma unroll
    for (int ps = 0; ps < 4; ++ps) {
        int idx = ps * 2048 + tid * 8;
        int px = idx >> 8, ch = idx & 255;
        *(bf16x8*)&Bs[px][ch] = *(const bf16x8*)(inT + (size_t)(pbase + px) * 256 + ch);
    }
    __syncthreads();
    f32x4 acc[4][2];
#pragma unroll
    for (int i = 0; i < 4; ++i)
#pragma unroll
        for (int j = 0; j < 2; ++j) acc[i][j] = (f32x4){0.f, 0.f, 0.f, 0.f};
#pragma unroll
    for (int kss = 0; kss < 8; ++kss) {
        int ks = kss << 5;
        bf16x8 af[4], bfr[2];
#pragma unroll
        for (int mi = 0; mi < 4; ++mi)
            af[mi] = *(const bf16x8*)(wh + (size_t)((wv << 6) + (mi << 4) + lr) * 256 + ks + (lg << 3));
#pragma unroll
        for (int ni = 0; ni < 2; ++ni)
            bfr[ni] = *(const bf16x8*)(&Bs[(ni << 4) + lr][ks + (lg << 3)]);
#pragma unroll
        for (int mi = 0; mi < 4; ++mi)
#pragma unroll
            for (int ni = 0; ni < 2; ++ni)
                acc[mi][ni] = __builtin_amdgcn_mfma_f32_16x16x32_bf16(
                    af[mi], bfr[ni], acc[mi][ni], 0, 0, 0);
    }
#pragma unroll
    for (int mi = 0; mi < 4; ++mi)
#pragma unroll
        for (int ni = 0; ni < 2; ++ni) {
            int pxx = pc0 + (ni << 4) + lr;
            int pix = (hrow + 1) * 130 + pxx + 1;
            unsigned short pk[4];
#pragma unroll
            for (int r = 0; r < 4; ++r) pk[r] = f2bf(acc[mi][ni][r]);
            *(ushort4*)(ccT + (size_t)pix * 512 + 256 + (wv << 6) + (mi << 4) + (lg << 2))
                = *(ushort4*)pk;
        }
}

// ============ offset conv 512->18 v2: stage-once halo, 1 barrier ============
__global__ __launch_bounds__(256, 2) void off_part2_k(
        const unsigned short* __restrict__ ccT,   // [130*130][512] bf16
        const unsigned short* __restrict__ pwTh,  // [9][32][512] bf16
        float* __restrict__ pbuf) {               // [4][32][HW] f32
    __shared__ __align__(16) unsigned short Ls[198][132];   // 52,272 B
    int b = blockIdx.x;                   // 1024 blocks
    int xcd = b & 7, slot = b >> 3;       // 128 slots/XCD
    int hrow = (xcd << 4) + (slot >> 3);  // XCD owns 16 contiguous hrows
    int rest = slot & 7;
    int pxh = rest >> 2, cg = rest & 3;
    int pc0h = pxh << 6, c0 = cg << 7;
    int tid = threadIdx.x;
    int wv = tid >> 6, lane = tid & 63;
    int lr = lane & 15, lg = lane >> 4;
    int wo = wv & 1;                      // o-tile (16 o of 32)
    int pt0 = (wv >> 1) << 1;             // first of 2 px-tiles for this wave
    int chk = tid & 15, pxi0 = tid >> 4;
#pragma unroll
    for (int r = 0; r < 3; ++r) {
        const unsigned short* src = ccT + (size_t)((hrow + r) * 130 + pc0h) * 512 + c0;
        for (int pxi = pxi0; pxi < 66; pxi += 16)
            *(bf16x8*)&Ls[r * 66 + pxi][chk << 3] =
                *(const bf16x8*)(src + (size_t)pxi * 512 + (chk << 3));
    }
    __syncthreads();

    f32x4 acc[2];
    acc[0] = (f32x4){0.f, 0.f, 0.f, 0.f};
    acc[1] = (f32x4){0.f, 0.f, 0.f, 0.f};
    for (int kt = 0; kt < 9; ++kt) {
        int rowb = (kt / 3) * 66 + (kt % 3);
        const unsigned short* wk = pwTh + (size_t)kt * 16384
                                 + (size_t)((wo << 4) + lr) * 512 + c0;
#pragma unroll
        for (int ks = 0; ks < 128; ks += 32) {
            bf16x8 af = *(const bf16x8*)(wk + ks + (lg << 3));
#pragma unroll
            for (int pi = 0; pi < 2; ++pi) {
                int px = ((pt0 + pi) << 4) + lr;
                bf16x8 bfr = *(const bf16x8*)(&Ls[rowb + px][ks + (lg << 3)]);
                acc[pi] = __builtin_amdgcn_mfma_f32_16x16x32_bf16(af, bfr, acc[pi], 0, 0, 0);
            }
        }
    }
#pragma unroll
    for (int pi = 0; pi < 2; ++pi)
#pragma unroll
        for (int r = 0; r < 4; ++r) {
            int o = (wo << 4) + (lg << 2) + r;
            int p = (hrow << 7) + pc0h + ((pt0 + pi) << 4) + lr;
            pbuf[(size_t)((cg << 5) + o) * HW + p] = acc[pi][r];
        }
}

// ---- per-(pixel,k): sum 4 partials; IDX = pixel-index*512 into ccT ---------
__global__ __launch_bounds__(256) void make_idx_k(const float* __restrict__ pbuf,
                                                  const float* __restrict__ pb,
                                                  int4* __restrict__ IDX,
                                                  float4* __restrict__ WT) {
    int t = blockIdx.x * 256 + threadIdx.x;
    if (t >= 9 * HW) return;
    int k = t >> 14, p = t & 16383;
    int h = p >> 7, w = p & 127;
    float ox = 0.f, oy = 0.f;
#pragma unroll
    for (int cg = 0; cg < 4; ++cg) {
        ox += pbuf[(size_t)((cg << 5) + k) * HW + p];
        oy += pbuf[(size_t)((cg << 5) + 9 + k) * HW + p];
    }
    float px = ox + pb[k]     + (float)(k / 3 - 1) + (float)(h + 1);
    float py = oy + pb[9 + k] + (float)(k % 3 - 1) + (float)(w + 1);
    float fx = floorf(px), fy = floorf(py);
    float x0 = fminf(fmaxf(fx,        0.f), 129.f);
    float x1 = fminf(fmaxf(fx + 1.0f, 0.f), 129.f);
    float y0 = fminf(fmaxf(fy,        0.f), 129.f);
    float y1 = fminf(fmaxf(fy + 1.0f, 0.f), 129.f);
    float pxc = fminf(fmaxf(px, 0.f), 129.f);
    float pyc = fminf(fmaxf(py, 0.f), 129.f);
    float gx0 = 1.0f + x0 - pxc, gx1 = 1.0f - x1 + pxc;
    float gy0 = 1.0f + y0 - pyc, gy1 = 1.0f - y1 + pyc;
    int ix0 = (int)x0, ix1 = (int)x1, iy0 = (int)y0, iy1 = (int)y1;
    IDX[t] = make_int4((ix0 * 130 + iy0) << 9, (ix1 * 130 + iy1) << 9,
                       (ix0 * 130 + iy1) << 9, (ix1 * 130 + iy0) << 9);
    WT[t]  = make_float4(gx0 * gy0, gx1 * gy1, gx0 * gy1, gx1 * gy0);
}

// ============ deformable contraction v10 (FROZEN at fam9, 74us) =============
__global__ __launch_bounds__(512, 4) void fam9_k(
        const unsigned short* __restrict__ ccT,    // [130*130][512] bf16
        const unsigned short* __restrict__ dcwF,   // [72][8][2][2][64][8] bf16
        const int4* __restrict__ IDX, const float4* __restrict__ WT,
        unsigned short* __restrict__ part0,        // [HW][256] bf16
        unsigned short* __restrict__ part1) {      // [HW][256] bf16
    __shared__ __align__(16) unsigned short Bs[2][64][72];   // 18,432 B
    int b = blockIdx.x;                 // 512 blocks
    int khalf = b >> 8;                 // K-half: chunks [0,36) or [36,72)
    int bb = b & 255;
    int xcd = bb & 7, sl = bb >> 3;     // 32 slots per XCD
    int nt = (xcd << 5) + sl;           // XCD owns 16 contiguous hrows
    int hrow = nt >> 1, pc0 = (nt & 1) << 6;
    int tid = threadIdx.x;
    int wv = tid >> 6, lane = tid & 63;
    int lr = lane & 15, lg = lane >> 4;
    int pxg = tid >> 3, grp = tid & 7;  // gather: 64 px x 8 ch-groups of 16B
    int p2 = (hrow << 7) + pc0 + pxg;   // this thread's gather pixel
    const unsigned short* wfb = dcwF + ((size_t)wv << 11) + ((size_t)lane << 3);
    f32x4 acc[2][4];
#pragma unroll
    for (int i = 0; i < 2; ++i)
#pragma unroll
        for (int j = 0; j < 4; ++j) acc[i][j] = (f32x4){0.f, 0.f, 0.f, 0.f};

    bf16x8 v0, v1, v2, v3;              // gather regs (single set)
    bf16x8 Aa00, Aa01, Aa10, Aa11;      // A-frag set A (even chunks)
    bf16x8 Ba00, Ba01, Ba10, Ba11;      // A-frag set B (odd chunks)

#define ISSUE_A9(S, ch) do {                                                  \
    const unsigned short* ap_ = wfb + ((size_t)(ch) << 14);                   \
    S##00 = *(const bf16x8*)(ap_);                                            \
    S##01 = *(const bf16x8*)(ap_ + 512);                                      \
    S##10 = *(const bf16x8*)(ap_ + 1024);                                     \
    S##11 = *(const bf16x8*)(ap_ + 1536);                                     \
} while (0)

#define ISSUE_G9(ch, idm) do {                                                \
    int cb_ = (((ch) & 7) << 6) + (grp << 3);                                 \
    v0 = *(const bf16x8*)(ccT + (idm).x + cb_);                               \
    v1 = *(const bf16x8*)(ccT + (idm).y + cb_);                               \
    v2 = *(const bf16x8*)(ccT + (idm).z + cb_);                               \
    v3 = *(const bf16x8*)(ccT + (idm).w + cb_);                               \
} while (0)

#define NEXT_G9(cn) do {                                                      \
    if ((cn) < c1) {                                                          \
        if (((cn) & 7) == 0) {                                                \
            idc = idn; wtc = wtn;                                             \
            int kt2_ = ((cn) >> 3) + 1;                                       \
            if ((kt2_ << 3) < c1) {                                           \
                idn = IDX[(kt2_ << 14) + p2];                                 \
                wtn = WT [(kt2_ << 14) + p2];                                 \
            }                                                                 \
        }                                                                     \
        ISSUE_G9(cn, idc);                                                    \
        wnext = wtc;                                                          \
    }                                                                         \
} while (0)

#define PUBLISH9(bi) do {                                                     \
    unsigned short pk_[8];                                                    \
    _Pragma("unroll")                                                         \
    for (int e_ = 0; e_ < 8; ++e_) {                                          \
        float val_ = wcur.x * bf2f((unsigned short)v0[e_])                    \
                   + wcur.y * bf2f((unsigned short)v1[e_])                    \
                   + wcur.z * bf2f((unsigned short)v2[e_])                    \
                   + wcur.w * bf2f((unsigned short)v3[e_]);                   \
        pk_[e_] = f2bf(val_);                                                 \
    }                                                                         \
    *(bf16x8*)&Bs[bi][pxg][grp << 3] = *(bf16x8*)pk_;                         \
} while (0)

#define MFMA9(S, bi) do {                                                     \
    _Pragma("unroll")                                                         \
    for (int ni_ = 0; ni_ < 4; ++ni_) {                                       \
        bf16x8 b0_ = *(const bf16x8*)(&Bs[bi][(ni_ << 4) + lr][lg << 3]);     \
        acc[0][ni_] = __builtin_amdgcn_mfma_f32_16x16x32_bf16(S##00, b0_, acc[0][ni_], 0, 0, 0); \
        acc[1][ni_] = __builtin_amdgcn_mfma_f32_16x16x32_bf16(S##01, b0_, acc[1][ni_], 0, 0, 0); \
    }                                                                         \
    _Pragma("unroll")                                                         \
    for (int ni_ = 0; ni_ < 4; ++ni_) {                                       \
        bf16x8 b1_ = *(const bf16x8*)(&Bs[bi][(ni_ << 4) + lr][32 + (lg << 3)]); \
        acc[0][ni_] = __builtin_amdgcn_mfma_f32_16x16x32_bf16(S##10, b1_, acc[0][ni_], 0, 0, 0); \
        acc[1][ni_] = __builtin_amdgcn_mfma_f32_16x16x32_bf16(S##11, b1_, acc[1][ni_], 0, 0, 0); \
    }                                                                         \
} while (0)

    int c0 = khalf * 36, c1 = c0 + 36;
    int kt0 = c0 >> 3;
    int4   idc = IDX[(kt0 << 14) + p2];
    float4 wtc = WT [(kt0 << 14) + p2];
    int4   idn = IDX[((kt0 + 1) << 14) + p2];
    float4 wtn = WT [((kt0 + 1) << 14) + p2];
    ISSUE_G9(c0, idc);
    float4 wcur = wtc, wnext = wtc;
    ISSUE_A9(Aa, c0);

    for (int c = c0; c < c1; c += 2) {
        // even chunk c -> Bs[0], consumes Aa
        PUBLISH9(0);                    // weighting of gather(c)
        NEXT_G9(c + 1);                 // gather(c+1) in flight across MFMA(c)
        ISSUE_A9(Ba, c + 1);            // A(c+1) in flight across MFMA(c)
        __syncthreads();                // publish(c) visible; MFMA(c-1) done
        MFMA9(Aa, 0);
        wcur = wnext;
        // odd chunk c+1 -> Bs[1], consumes Ba
        PUBLISH9(1);
        NEXT_G9(c + 2);
        if (c + 2 < c1) ISSUE_A9(Aa, c + 2);
        __syncthreads();
        MFMA9(Ba, 1);
        wcur = wnext;
    }
#undef ISSUE_A9
#undef ISSUE_G9
#undef NEXT_G9
#undef PUBLISH9
#undef MFMA9

    unsigned short* pt = khalf ? part1 : part0;
#pragma unroll
    for (int mi = 0; mi < 2; ++mi)
#pragma unroll
        for (int ni = 0; ni < 4; ++ni) {
            int pxx = pc0 + (ni << 4) + lr;
            int p = (hrow << 7) + pxx;
            unsigned short pk[4];
#pragma unroll
            for (int r = 0; r < 4; ++r) pk[r] = f2bf(acc[mi][ni][r]);
            *(ushort4*)(pt + (size_t)p * 256 + (wv << 5) + (mi << 4) + (lg << 2))
                = *(ushort4*)pk;
        }
}

// ---- famT interior = part0 + part1 + Cf(from ccT), all pixel-major ---------
__global__ __launch_bounds__(256) void combineT_k(
        const unsigned short* __restrict__ p0,    // [HW][256]
        const unsigned short* __restrict__ p1,    // [HW][256]
        const unsigned short* __restrict__ ccT,   // [130*130][512], Cf at +256
        unsigned short* __restrict__ famT) {      // [130*130][256]
    int t = blockIdx.x * 256 + threadIdx.x;       // 524,288 = HW*32
    int o8 = (t & 31) << 3, p = t >> 5;
    int row = p >> 7, col = p & 127;
    int pix = (row + 1) * 130 + col + 1;
    bf16x8 a = *(const bf16x8*)(p0 + (size_t)p * 256 + o8);
    bf16x8 b = *(const bf16x8*)(p1 + (size_t)p * 256 + o8);
    bf16x8 c = *(const bf16x8*)(ccT + (size_t)pix * 512 + 256 + o8);
    unsigned short out[8];
#pragma unroll
    for (int e = 0; e < 8; ++e)
        out[e] = f2bf(bf2f((unsigned short)a[e]) + bf2f((unsigned short)b[e])
                      + bf2f((unsigned short)c[e]));
    *(bf16x8*)(famT + (size_t)pix * 256 + o8) = *(bf16x8*)out;
}

// ============ 3x3 conv 256->256 v2: stage-once pixel-major, 1 barrier =======
__global__ __launch_bounds__(256, 2) void conv2T_k(
        const unsigned short* __restrict__ inT,   // [130*130][256] bf16, ring=0
        const unsigned short* __restrict__ wF,    // frag-major [9][4][8][4][64][8]
        const float* __restrict__ gam, const float* __restrict__ bet,
        const float* __restrict__ mean, const float* __restrict__ var,
        float* __restrict__ out_flat,             // [256][HW] f32
        unsigned short* __restrict__ out_padT) {  // optional [130*130][256]
    __shared__ __align__(16) unsigned short Ls[102][264];   // 53,856 B
    __shared__ float scs[256], bis[256];
    int b = blockIdx.x;
    int xcd = b & 7, slot = b >> 3;
    int nt = (xcd << 6) + slot;
    int hrow = nt >> 2, pc0 = (nt & 3) << 5;
    int tid = threadIdx.x;
    int wv = tid >> 6, lane = tid & 63;
    int lr = lane & 15, lg = lane >> 4;
    {
        float sc = gam[tid] * rsqrtf(var[tid] + 1e-5f);
        scs[tid] = sc;
        bis[tid] = bet[tid] - mean[tid] * sc;
    }
#pragma unroll
    for (int r = 0; r < 3; ++r) {
        const unsigned short* src = inT + (size_t)((hrow + r) * 130 + pc0) * 256;
#pragma unroll
        for (int ps = 0; ps < 5; ++ps) {
            int idx = ps * 2048 + tid * 8;
            if (idx < 8704) {                     // 34*256
                bf16x8 v = *(const bf16x8*)(src + idx);
                *(bf16x8*)&Ls[r * 34 + (idx >> 8)][idx & 255] = v;
            }
        }
    }
    __syncthreads();

    f32x4 acc[4][2];
#pragma unroll
    for (int i = 0; i < 4; ++i)
#pragma unroll
        for (int j = 0; j < 2; ++j) acc[i][j] = (f32x4){0.f, 0.f, 0.f, 0.f};

    const unsigned short* wvb = wF + ((size_t)wv << 14) + ((size_t)lane << 3);
    for (int kt = 0; kt < 9; ++kt) {
        int rowb = (kt / 3) * 34 + (kt % 3);
        const unsigned short* wkb = wvb + (size_t)kt * 65536;
#pragma unroll
        for (int kss = 0; kss < 8; ++kss) {
            int ks = kss << 5;
            bf16x8 af[4], bfr[2];
#pragma unroll
            for (int mi = 0; mi < 4; ++mi)
                af[mi] = *(const bf16x8*)(wkb + (size_t)kss * 2048 + mi * 512);
#pragma unroll
            for (int ni = 0; ni < 2; ++ni)
                bfr[ni] = *(const bf16x8*)(&Ls[rowb + (ni << 4) + lr][ks + (lg << 3)]);
#pragma unroll
            for (int mi = 0; mi < 4; ++mi)
#pragma unroll
                for (int ni = 0; ni < 2; ++ni)
                    acc[mi][ni] = __builtin_amdgcn_mfma_f32_16x16x32_bf16(
                        af[mi], bfr[ni], acc[mi][ni], 0, 0, 0);
        }
    }

#pragma unroll
    for (int mi = 0; mi < 4; ++mi)
#pragma unroll
        for (int ni = 0; ni < 2; ++ni) {
            int pxx = pc0 + (ni << 4) + lr;
            unsigned short pk[4];
#pragma unroll
            for (int r = 0; r < 4; ++r) {
                int o = (wv << 6) + (mi << 4) + (lg << 2) + r;
                float rv = fmaxf(acc[mi][ni][r] * scs[o] + bis[o], 0.0f);
                out_flat[(size_t)o * HW + (hrow << 7) + pxx] = rv;
                pk[r] = f2bf(rv);
            }
            if (out_padT) {
                int pix = (hrow + 1) * 130 + pxx + 1;
                *(ushort4*)(out_padT + (size_t)pix * 256 + (wv << 6) + (mi << 4) + (lg << 2))
                    = *(ushort4*)pk;
            }
        }
}

extern "C" void kernel_launch(void* const* d_in, const int* in_sizes, int n_in,
                              void* d_out, int out_size, void* d_ws, size_t ws_size,
                              hipStream_t stream) {
    const float* x     = (const float*)d_in[0];
    const float* llf   = (const float*)d_in[1];
    const float* fm_w  = (const float*)d_in[2];
    const float* fs_w  = (const float*)d_in[3];
    const float* p_w   = (const float*)d_in[4];
    const float* p_b   = (const float*)d_in[5];
    const float* dc_w  = (const float*)d_in[6];
    const float* lc1_w = (const float*)d_in[7];
    const float* bn1g  = (const float*)d_in[8];
    const float* bn1b  = (const float*)d_in[9];
    const float* bn1m  = (const float*)d_in[10];
    const float* bn1v  = (const float*)d_in[11];
    const float* lc2_w = (const float*)d_in[12];
    const float* bn2g  = (const float*)d_in[13];
    const float* bn2b  = (const float*)d_in[14];
    const float* bn2m  = (const float*)d_in[15];
    const float* bn2v  = (const float*)d_in[16];
    float* out1 = (float*)d_out;
    float* out2 = out1 + (size_t)256 * HW;

    // d_out is WRITE-ONLY (pure outputs). All scratch lives in ws.
    if (ws_size < 79839232u) return;
    char* ws = (char*)d_ws;
    unsigned short* ccT   = (unsigned short*)ws;                // [0, 17,305,600)
    float*          xTf   = (float*)(ws + 17305600);            // 1MB, dead after up_cvtT
    float*          vbuf  = (float*)(ws + 17305600);
    unsigned short* famT  = (unsigned short*)(ws + 17305600);   // [130*130][256]
    unsigned short* up1T  = (unsigned short*)(ws + 26091520);   // [130*130][256]
    unsigned short* llfT  = (unsigned short*)(ws + 34877440);   // dead after vmfma
    unsigned short* uT    = (unsigned short*)(ws + 43266048);   // dead after cfmfma
    unsigned short* part0 = (unsigned short*)(ws + 43266048);   // fam9 partial khalf=0
    unsigned short* fmwh  = (unsigned short*)(ws + 51654656);   // 131,072
    unsigned short* fswh  = (unsigned short*)(ws + 51785728);   // 131,072
    float*          ubuf  = (float*)(ws + 51916800);            // U region
    float*          pbuf  = (float*)(ws + 51916800);            // dead after make_idx
    unsigned short* part1 = (unsigned short*)(ws + 51916800);   // fam9 partial khalf=1
    int4*           IDX   = (int4*)  (ws + 60305408);
    float4*         WT    = (float4*)(ws + 62664704);
    unsigned short* dcwF   = (unsigned short*)(ws + 68694016);  // 2,359,296 (frag-major)
    unsigned short* lcw1F  = (unsigned short*)(ws + 71053312);  // 1,179,648
    unsigned short* lcw2F  = (unsigned short*)(ws + 72232960);  // 1,179,648
    unsigned short* pwTh   = (unsigned short*)(ws + 73412608);  //   294,912

    xT_k<<<dim3(1024), 256, 0, stream>>>(x, xTf);
    up_cvtT_k<<<dim3(16900), 256, 0, stream>>>(xTf, ccT);         // ccT ch 0..255 (+ring0)
    cvtT_tile_k<<<dim3(256, 4), 256, 0, stream>>>(llf, llfT);
    w2bf_k<<<dim3(256), 256, 0, stream>>>(fm_w, fs_w, fmwh, fswh);
    vmfma2_k<<<dim3(512), 256, 0, stream>>>(llfT, fmwh, vbuf);    // llfT dead after
    u_matmul_k<<<dim3(2, 256), 256, 0, stream>>>(llf, vbuf, ubuf);  // vbuf dead after
    cvtT_tile_k<<<dim3(256, 4), 256, 0, stream>>>(ubuf, uT);      // ubuf dead after
    tr_dcwF9_k<<<dim3(4608), 256, 0, stream>>>(dc_w, dcwF);       // wave-slice frag-major
    tr_lcF2_k<<<dim3(2304, 2), 256, 0, stream>>>(lc1_w, lc2_w, lcw1F, lcw2F);
    tr_pw_k<<<dim3(576), 256, 0, stream>>>(p_w, pwTh);
    cfmfma2_k<<<dim3(512), 256, 0, stream>>>(uT, fswh, ccT);      // uT dead after
    ringT_k<<<dim3(520), 256, 0, stream>>>(ccT);                  // Cf ring = 0
    off_part2_k<<<dim3(1024), 256, 0, stream>>>(ccT, pwTh, pbuf);
    make_idx_k<<<dim3(576), 256, 0, stream>>>(pbuf, p_b, IDX, WT);  // pbuf dead after
    zero_ringP2_k<<<dim3(130), 256, 0, stream>>>(famT, up1T);
    fam9_k<<<dim3(512), 512, 0, stream>>>(ccT, dcwF, IDX, WT, part0, part1);
    combineT_k<<<dim3(2048), 256, 0, stream>>>(part0, part1, ccT, famT);
    conv2T_k<<<dim3(512), 256, 0, stream>>>(famT, lcw1F, bn1g, bn1b, bn1m, bn1v,
                                            out1, up1T);
    conv2T_k<<<dim3(512), 256, 0, stream>>>(up1T, lcw2F, bn2g, bn2b, bn2m, bn2v,
                                            out2, nullptr);
}

// Round 13
// 385.543 us; speedup vs baseline: 1.0641x; 1.0265x over previous
//
#include <hip/hip_runtime.h>
#include <math.h>

#define HW   16384           // 128*128
#define PS   16900           // 130*130 padded plane

typedef __attribute__((ext_vector_type(8))) short bf16x8;
typedef __attribute__((ext_vector_type(4))) float f32x4;

__device__ inline unsigned short f2bf(float x) {
    unsigned int u = __float_as_uint(x);
    unsigned int r = (u + 0x7fffu + ((u >> 16) & 1u)) >> 16;
    return (unsigned short)r;
}
__device__ inline float bf2f(unsigned short h) {
    return __uint_as_float(((unsigned int)h) << 16);
}

// ---- zero ring pixels (all 256 ch) of TWO pixel-major [130*130][256] bufs --
__global__ __launch_bounds__(256) void zero_ringP2_k(unsigned short* __restrict__ b0,
                                                     unsigned short* __restrict__ b1) {
    int t = blockIdx.x * 256 + threadIdx.x;
    if (t >= 2 * 520 * 32) return;
    unsigned short* base = (t >= 520 * 32) ? b1 : b0;
    int tt = (t >= 520 * 32) ? t - 520 * 32 : t;
    int ck = (tt & 31) << 3, rp = tt >> 5;
    int row, col;
    if (rp < 130)      { row = 0;   col = rp; }
    else if (rp < 260) { row = 129; col = rp - 130; }
    else {
        int rem = rp - 260;
        if (rem >= 256) return;            // rows 1..128 only
        row = 1 + (rem >> 1); col = (rem & 1) ? 129 : 0;
    }
    bf16x8 z = (bf16x8){0, 0, 0, 0, 0, 0, 0, 0};
    *(bf16x8*)(base + (size_t)(row * 130 + col) * 256 + ck) = z;
}

// ---- zero ccT ring pixels for channels 256..511 (Cf) -----------------------
__global__ __launch_bounds__(256) void ringT_k(unsigned short* __restrict__ ccT) {
    int t = blockIdx.x * 256 + threadIdx.x;
    if (t >= 520 * 256) return;
    int ci = t & 255, rp = t >> 8;
    int row, col;
    if (rp < 130)      { row = 0;   col = rp; }
    else if (rp < 260) { row = 129; col = rp - 130; }
    else {
        int rem = rp - 260;
        if (rem >= 256) return;            // rows 1..128 only (no OOB spill)
        row = 1 + (rem >> 1); col = (rem & 1) ? 129 : 0;
    }
    ccT[(size_t)(row * 130 + col) * 512 + 256 + ci] = 0;
}

// ---- x (256,32,32) f32 plane-major -> xT [1024][256] f32 (tiny, 1MB) -------
__global__ __launch_bounds__(256) void xT_k(const float* __restrict__ x,
                                            float* __restrict__ xT) {
    int t = blockIdx.x * 256 + threadIdx.x;    // 262,144
    int c = t & 255, pos = t >> 8;
    xT[t] = x[(size_t)c * 1024 + pos];
}

// ---- fused bilinear upsample + transpose-cvt: xT -> ccT ch 0..255 ----------
__global__ __launch_bounds__(256) void up_cvtT_k(const float* __restrict__ xT,
                                                 unsigned short* __restrict__ ccT) {
    int pix = blockIdx.x;                      // 0..16899
    int c = threadIdx.x;
    int r = pix / 130, s = pix - r * 130;
    float val = 0.0f;
    if (r >= 1 && r <= 128 && s >= 1 && s <= 128) {
        int i = r - 1, j = s - 1;
        float yf = (float)i * (31.0f / 127.0f);
        float xf = (float)j * (31.0f / 127.0f);
        int y0 = min((int)yf, 31); int y1 = min(y0 + 1, 31);
        int x0 = min((int)xf, 31); int x1 = min(x0 + 1, 31);
        float wy = yf - (float)y0, wx = xf - (float)x0;
        float v00 = xT[(size_t)(y0 * 32 + x0) * 256 + c];
        float v01 = xT[(size_t)(y0 * 32 + x1) * 256 + c];
        float v10 = xT[(size_t)(y1 * 32 + x0) * 256 + c];
        float v11 = xT[(size_t)(y1 * 32 + x1) * 256 + c];
        float a = v00 * (1.0f - wx) + v01 * wx;
        float b = v10 * (1.0f - wx) + v11 * wx;
        val = a * (1.0f - wy) + b * wy;
    }
    ccT[(size_t)pix * 512 + c] = f2bf(val);
}

// ---- LDS-tiled transpose+cvt: f32 [256][HW] -> bf16 [HW][256] --------------
__global__ __launch_bounds__(256) void cvtT_tile_k(const float* __restrict__ src,
                                                   unsigned short* __restrict__ dst) {
    __shared__ float Ls[64][65];               // 16,640 B
    int px0 = blockIdx.x << 6;                 // 256 px-tiles
    int c0  = blockIdx.y << 6;                 // 4 ch-tiles
    int t = threadIdx.x;
    int pxl = t & 63, cq = t >> 6;             // cq 0..3
#pragma unroll
    for (int it = 0; it < 16; ++it) {
        int cl = (it << 2) + cq;
        Ls[cl][pxl] = src[(size_t)(c0 + cl) * HW + px0 + pxl];
    }
    __syncthreads();
    int c8 = (t & 7) << 3;                     // 0,8,...,56
    int pxb = t >> 3;                          // 0..31
#pragma unroll
    for (int rr = 0; rr < 2; ++rr) {
        int px = pxb + (rr << 5);
        unsigned short pk[8];
#pragma unroll
        for (int e = 0; e < 8; ++e) pk[e] = f2bf(Ls[c8 + e][px]);
        *(bf16x8*)(dst + (size_t)(px0 + px) * 256 + c0 + c8) = *(bf16x8*)pk;
    }
}

// ---- fm_w / fs_w (256x256 f32) -> bf16 -------------------------------------
__global__ __launch_bounds__(256) void w2bf_k(const float* __restrict__ a,
                                              const float* __restrict__ b,
                                              unsigned short* __restrict__ da,
                                              unsigned short* __restrict__ db) {
    int t = blockIdx.x * 256 + threadIdx.x;
    if (t >= 65536) return;
    da[t] = f2bf(a[t]);
    db[t] = f2bf(b[t]);
}

// ---- u[c,h,w] = sum_k L[c,h,k]*v[c,k,w] + L[c,h,w] (f32) -------------------
__global__ __launch_bounds__(256) void u_matmul_k(const float* __restrict__ llf,
                                                  const float* __restrict__ v,
                                                  float* __restrict__ u) {
    int c = blockIdx.y;
    const float* L = llf + (size_t)c * HW;
    const float* V = v   + (size_t)c * HW;
    float*       U = u   + (size_t)c * HW;
    int tid = threadIdx.x;
    int ty = tid >> 4, tx = tid & 15;
    int r0 = (blockIdx.x << 6) + (ty << 2);
    int w0 = tx << 3;
    float acc[4][8] = {};
    for (int k = 0; k < 128; ++k) {
        float a[4];
#pragma unroll
        for (int i = 0; i < 4; ++i) a[i] = L[(r0 + i) * 128 + k];
        float4 b0 = *(const float4*)(V + k * 128 + w0);
        float4 b1 = *(const float4*)(V + k * 128 + w0 + 4);
        float bv[8] = {b0.x, b0.y, b0.z, b0.w, b1.x, b1.y, b1.z, b1.w};
#pragma unroll
        for (int i = 0; i < 4; ++i)
#pragma unroll
            for (int j = 0; j < 8; ++j) acc[i][j] += a[i] * bv[j];
    }
#pragma unroll
    for (int i = 0; i < 4; ++i) {
#pragma unroll
        for (int j = 0; j < 8; ++j) acc[i][j] += L[(r0 + i) * 128 + w0 + j];
        *(float4*)(U + (r0 + i) * 128 + w0)     = make_float4(acc[i][0], acc[i][1], acc[i][2], acc[i][3]);
        *(float4*)(U + (r0 + i) * 128 + w0 + 4) = make_float4(acc[i][4], acc[i][5], acc[i][6], acc[i][7]);
    }
}

// ---- dc_w (256,512,3,3) f32 -> wave-slice fragment-major bf16 --------------
__global__ __launch_bounds__(256) void tr_dcwF9_k(const float* __restrict__ w,
                                                  unsigned short* __restrict__ dst) {
    int t = blockIdx.x * 256 + threadIdx.x;
    if (t >= 1179648) return;                 // 72*8*2*2*64*8
    int e    = t & 7;
    int lane = (t >> 3) & 63;
    int f    = t >> 9;                        // frag index
    int mi   = f & 1;
    int s    = (f >> 1) & 1;
    int wv   = (f >> 2) & 7;
    int ch   = f >> 5;                        // chunk 0..71
    int kt   = ch >> 3;
    int o = (wv << 5) + (mi << 4) + (lane & 15);
    int c = ((ch & 7) << 6) + (s << 5) + ((lane >> 4) << 3) + e;
    dst[t] = f2bf(w[(size_t)o * 4608 + c * 9 + kt]);
}

// ---- lc weights (256,256,3,3) f32 -> fragment-major bf16 (both in one) -----
__global__ __launch_bounds__(256) void tr_lcF2_k(const float* __restrict__ w1,
                                                 const float* __restrict__ w2,
                                                 unsigned short* __restrict__ d1,
                                                 unsigned short* __restrict__ d2) {
    const float* w = blockIdx.y ? w2 : w1;
    unsigned short* dst = blockIdx.y ? d2 : d1;
    int t = blockIdx.x * 256 + threadIdx.x;
    if (t >= 589824) return;                  // 9*4*8*4*64*8
    int e    = t & 7;
    int lane = (t >> 3) & 63;
    int mi   = (t >> 9) & 3;
    int kss  = (t >> 11) & 7;
    int wo   = (t >> 14) & 3;
    int kt   = t >> 16;
    int o = (wo << 6) + (mi << 4) + (lane & 15);
    int c = (kss << 5) + ((lane >> 4) << 3) + e;
    dst[t] = f2bf(w[(size_t)o * 2304 + c * 9 + kt]);
}

// ---- p_w (18,512,3,3) f32 -> [k][32][512] bf16, zero-padded to 32 o --------
__global__ __launch_bounds__(256) void tr_pw_k(const float* __restrict__ w,
                                               unsigned short* __restrict__ dst) {
    int t = blockIdx.x * 256 + threadIdx.x;
    if (t >= 9 * 32 * 512) return;
    int c = t & 511; int rest = t >> 9; int o = rest & 31; int k = rest >> 5;
    dst[t] = (o < 18) ? f2bf(w[(size_t)o * 4608 + c * 9 + k]) : (unsigned short)0;
}

// ============ 1x1 GEMM v2: stage-once 32px x 256ch, 1 barrier, + sigmoid ====
__global__ __launch_bounds__(256, 2) void vmfma2_k(
        const unsigned short* __restrict__ inT,   // [HW][256] bf16
        const unsigned short* __restrict__ wh,    // [256][256] bf16
        float* __restrict__ vout) {               // [256][HW] f32
    __shared__ __align__(16) unsigned short Bs[32][264];     // 16,896 B
    int b = blockIdx.x;
    int xcd = b & 7, sl = b >> 3;
    int nt = (xcd << 6) + sl;
    int hrow = nt >> 2, pc0 = (nt & 3) << 5;
    int tid = threadIdx.x;
    int wv = tid >> 6, lane = tid & 63;
    int lr = lane & 15, lg = lane >> 4;
    int pbase = (hrow << 7) + pc0;
    // stage 32px x 256ch once (coalesced 512B/px rows)
#pragma unroll
    for (int ps = 0; ps < 4; ++ps) {
        int idx = ps * 2048 + tid * 8;
        int px = idx >> 8, ch = idx & 255;
        *(bf16x8*)&Bs[px][ch] = *(const bf16x8*)(inT + (size_t)(pbase + px) * 256 + ch);
    }
    __syncthreads();
    f32x4 acc[4][2];
#pragma unroll
    for (int i = 0; i < 4; ++i)
#pragma unroll
        for (int j = 0; j < 2; ++j) acc[i][j] = (f32x4){0.f, 0.f, 0.f, 0.f};
#pragma unroll
    for (int kss = 0; kss < 8; ++kss) {
        int ks = kss << 5;
        bf16x8 af[4], bfr[2];
#pragma unroll
        for (int mi = 0; mi < 4; ++mi)
            af[mi] = *(const bf16x8*)(wh + (size_t)((wv << 6) + (mi << 4) + lr) * 256 + ks + (lg << 3));
#pragma unroll
        for (int ni = 0; ni < 2; ++ni)
            bfr[ni] = *(const bf16x8*)(&Bs[(ni << 4) + lr][ks + (lg << 3)]);
#pragma unroll
        for (int mi = 0; mi < 4; ++mi)
#pragma unroll
            for (int ni = 0; ni < 2; ++ni)
                acc[mi][ni] = __builtin_amdgcn_mfma_f32_16x16x32_bf16(
                    af[mi], bfr[ni], acc[mi][ni], 0, 0, 0);
    }
#pragma unroll
    for (int mi = 0; mi < 4; ++mi)
#pragma unroll
        for (int ni = 0; ni < 2; ++ni)
#pragma unroll
            for (int r = 0; r < 4; ++r) {
                int o   = (wv << 6) + (mi << 4) + (lg << 2) + r;
                int pxx = pc0 + (ni << 4) + lr;
                vout[(size_t)o * HW + (hrow << 7) + pxx] =
                    1.0f / (1.0f + expf(-acc[mi][ni][r]));
            }
}

// ============ 1x1 GEMM v2: Cf -> ccT channels 256..511, stage-once ==========
__global__ __launch_bounds__(256, 2) void cfmfma2_k(
        const unsigned short* __restrict__ inT,   // uT [HW][256] bf16
        const unsigned short* __restrict__ wh,    // fs_w [256][256] bf16
        unsigned short* __restrict__ ccT) {       // [130*130][512] bf16
    __shared__ __align__(16) unsigned short Bs[32][264];     // 16,896 B
    int b = blockIdx.x;
    int xcd = b & 7, sl = b >> 3;
    int nt = (xcd << 6) + sl;
    int hrow = nt >> 2, pc0 = (nt & 3) << 5;
    int tid = threadIdx.x;
    int wv = tid >> 6, lane = tid & 63;
    int lr = lane & 15, lg = lane >> 4;
    int pbase = (hrow << 7) + pc0;
#pragma unroll
    for (int ps = 0; ps < 4; ++ps) {
        int idx = ps * 2048 + tid * 8;
        int px = idx >> 8, ch = idx & 255;
        *(bf16x8*)&Bs[px][ch] = *(const bf16x8*)(inT + (size_t)(pbase + px) * 256 + ch);
    }
    __syncthreads();
    f32x4 acc[4][2];
#pragma unroll
    for (int i = 0; i < 4; ++i)
#pragma unroll
        for (int j = 0; j < 2; ++j) acc[i][j] = (f32x4){0.f, 0.f, 0.f, 0.f};
#pragma unroll
    for (int kss = 0; kss < 8; ++kss) {
        int ks = kss << 5;
        bf16x8 af[4], bfr[2];
#pragma unroll
        for (int mi = 0; mi < 4; ++mi)
            af[mi] = *(const bf16x8*)(wh + (size_t)((wv << 6) + (mi << 4) + lr) * 256 + ks + (lg << 3));
#pragma unroll
        for (int ni = 0; ni < 2; ++ni)
            bfr[ni] = *(const bf16x8*)(&Bs[(ni << 4) + lr][ks + (lg << 3)]);
#pragma unroll
        for (int mi = 0; mi < 4; ++mi)
#pragma unroll
            for (int ni = 0; ni < 2; ++ni)
                acc[mi][ni] = __builtin_amdgcn_mfma_f32_16x16x32_bf16(
                    af[mi], bfr[ni], acc[mi][ni], 0, 0, 0);
    }
#pragma unroll
    for (int mi = 0; mi < 4; ++mi)
#pragma unroll
        for (int ni = 0; ni < 2; ++ni) {
            int pxx = pc0 + (ni << 4) + lr;
            int pix = (hrow + 1) * 130 + pxx + 1;
            unsigned short pk[4];
#pragma unroll
            for (int r = 0; r < 4; ++r) pk[r] = f2bf(acc[mi][ni][r]);
            *(ushort4*)(ccT + (size_t)pix * 512 + 256 + (wv << 6) + (mi << 4) + (lg << 2))
                = *(ushort4*)pk;
        }
}

// ============ offset conv 512->18 v3: 2-hrow blocks, stage-once, 1 barrier ==
// off_part2 had 1024 blocks x 52KB LDS -> only 3 blocks/CU fit (grid wants 4)
// => a 1/3-utilized tail round, and 3 strips staged per single output row
// (51.9MB aggregate). v3: each block handles an hrow PAIR, staging 4 shared
// strips (69.7KB LDS -> exactly 2 blocks/CU, 512 blocks = no tail). Staging
// 34.6MB (-33%); each af weight-load feeds 4 MFMAs (was 2).
__global__ __launch_bounds__(256, 2) void off_part2h_k(
        const unsigned short* __restrict__ ccT,   // [130*130][512] bf16
        const unsigned short* __restrict__ pwTh,  // [9][32][512] bf16
        float* __restrict__ pbuf) {               // [4][32][HW] f32
    __shared__ __align__(16) unsigned short Ls[264][132];   // 69,696 B
    int b = blockIdx.x;                   // 512 blocks
    int xcd = b & 7, slot = b >> 3;       // 64 slots/XCD
    int hp = (xcd << 3) + (slot >> 3);    // hrow-pair 0..63 (XCD-contiguous)
    int hrow0 = hp << 1;
    int rest = slot & 7;
    int pxh = rest >> 2, cg = rest & 3;
    int pc0h = pxh << 6, c0 = cg << 7;
    int tid = threadIdx.x;
    int wv = tid >> 6, lane = tid & 63;
    int lr = lane & 15, lg = lane >> 4;
    int wo = wv & 1;                      // o-tile (16 o of 32)
    int pt0 = (wv >> 1) << 1;             // first of 2 px-tiles for this wave
    int chk = tid & 15, pxi0 = tid >> 4;
    // stage 4 strips x 66 px x 128 ch (rows hrow0 .. hrow0+3, max 129)
#pragma unroll
    for (int r = 0; r < 4; ++r) {
        const unsigned short* src = ccT + (size_t)((hrow0 + r) * 130 + pc0h) * 512 + c0;
        for (int pxi = pxi0; pxi < 66; pxi += 16)
            *(bf16x8*)&Ls[r * 66 + pxi][chk << 3] =
                *(const bf16x8*)(src + (size_t)pxi * 512 + (chk << 3));
    }
    __syncthreads();

    f32x4 acc[2][2];
#pragma unroll
    for (int i = 0; i < 2; ++i)
#pragma unroll
        for (int j = 0; j < 2; ++j) acc[i][j] = (f32x4){0.f, 0.f, 0.f, 0.f};
    for (int kt = 0; kt < 9; ++kt) {
        int ktd = kt / 3, ktm = kt % 3;
        const unsigned short* wk = pwTh + (size_t)kt * 16384
                                 + (size_t)((wo << 4) + lr) * 512 + c0;
#pragma unroll
        for (int ks = 0; ks < 128; ks += 32) {
            bf16x8 af = *(const bf16x8*)(wk + ks + (lg << 3));
#pragma unroll
            for (int h2 = 0; h2 < 2; ++h2) {
                int rowb = (ktd + h2) * 66 + ktm;
#pragma unroll
                for (int pi = 0; pi < 2; ++pi) {
                    int px = ((pt0 + pi) << 4) + lr;
                    bf16x8 bfr = *(const bf16x8*)(&Ls[rowb + px][ks + (lg << 3)]);
                    acc[h2][pi] = __builtin_amdgcn_mfma_f32_16x16x32_bf16(
                        af, bfr, acc[h2][pi], 0, 0, 0);
                }
            }
        }
    }
#pragma unroll
    for (int h2 = 0; h2 < 2; ++h2)
#pragma unroll
        for (int pi = 0; pi < 2; ++pi)
#pragma unroll
            for (int r = 0; r < 4; ++r) {
                int o = (wo << 4) + (lg << 2) + r;
                int p = ((hrow0 + h2) << 7) + pc0h + ((pt0 + pi) << 4) + lr;
                pbuf[(size_t)((cg << 5) + o) * HW + p] = acc[h2][pi][r];
            }
}

// ---- per-(pixel,k): sum 4 partials; IDX = pixel-index*512 into ccT ---------
__global__ __launch_bounds__(256) void make_idx_k(const float* __restrict__ pbuf,
                                                  const float* __restrict__ pb,
                                                  int4* __restrict__ IDX,
                                                  float4* __restrict__ WT) {
    int t = blockIdx.x * 256 + threadIdx.x;
    if (t >= 9 * HW) return;
    int k = t >> 14, p = t & 16383;
    int h = p >> 7, w = p & 127;
    float ox = 0.f, oy = 0.f;
#pragma unroll
    for (int cg = 0; cg < 4; ++cg) {
        ox += pbuf[(size_t)((cg << 5) + k) * HW + p];
        oy += pbuf[(size_t)((cg << 5) + 9 + k) * HW + p];
    }
    float px = ox + pb[k]     + (float)(k / 3 - 1) + (float)(h + 1);
    float py = oy + pb[9 + k] + (float)(k % 3 - 1) + (float)(w + 1);
    float fx = floorf(px), fy = floorf(py);
    float x0 = fminf(fmaxf(fx,        0.f), 129.f);
    float x1 = fminf(fmaxf(fx + 1.0f, 0.f), 129.f);
    float y0 = fminf(fmaxf(fy,        0.f), 129.f);
    float y1 = fminf(fmaxf(fy + 1.0f, 0.f), 129.f);
    float pxc = fminf(fmaxf(px, 0.f), 129.f);
    float pyc = fminf(fmaxf(py, 0.f), 129.f);
    float gx0 = 1.0f + x0 - pxc, gx1 = 1.0f - x1 + pxc;
    float gy0 = 1.0f + y0 - pyc, gy1 = 1.0f - y1 + pyc;
    int ix0 = (int)x0, ix1 = (int)x1, iy0 = (int)y0, iy1 = (int)y1;
    IDX[t] = make_int4((ix0 * 130 + iy0) << 9, (ix1 * 130 + iy1) << 9,
                       (ix0 * 130 + iy1) << 9, (ix1 * 130 + iy0) << 9);
    WT[t]  = make_float4(gx0 * gy0, gx1 * gy1, gx0 * gy1, gx1 * gy0);
}

// ============ deformable contraction v10 (FROZEN at fam9, 74us) =============
// fam9's LDS pipe is ~90% busy with b128 ops at the 2-way aliasing minimum:
// structural roofline for this layout. fam10/fam11 spill-failures confirm the
// 64-VGPR budget is exactly consumed. Do not touch.
__global__ __launch_bounds__(512, 4) void fam9_k(
        const unsigned short* __restrict__ ccT,    // [130*130][512] bf16
        const unsigned short* __restrict__ dcwF,   // [72][8][2][2][64][8] bf16
        const int4* __restrict__ IDX, const float4* __restrict__ WT,
        unsigned short* __restrict__ part0,        // [HW][256] bf16
        unsigned short* __restrict__ part1) {      // [HW][256] bf16
    __shared__ __align__(16) unsigned short Bs[2][64][72];   // 18,432 B
    int b = blockIdx.x;                 // 512 blocks
    int khalf = b >> 8;                 // K-half: chunks [0,36) or [36,72)
    int bb = b & 255;
    int xcd = bb & 7, sl = bb >> 3;     // 32 slots per XCD
    int nt = (xcd << 5) + sl;           // XCD owns 16 contiguous hrows
    int hrow = nt >> 1, pc0 = (nt & 1) << 6;
    int tid = threadIdx.x;
    int wv = tid >> 6, lane = tid & 63;
    int lr = lane & 15, lg = lane >> 4;
    int pxg = tid >> 3, grp = tid & 7;  // gather: 64 px x 8 ch-groups of 16B
    int p2 = (hrow << 7) + pc0 + pxg;   // this thread's gather pixel
    const unsigned short* wfb = dcwF + ((size_t)wv << 11) + ((size_t)lane << 3);
    f32x4 acc[2][4];
#pragma unroll
    for (int i = 0; i < 2; ++i)
#pragma unroll
        for (int j = 0; j < 4; ++j) acc[i][j] = (f32x4){0.f, 0.f, 0.f, 0.f};

    bf16x8 v0, v1, v2, v3;              // gather regs (single set)
    bf16x8 Aa00, Aa01, Aa10, Aa11;      // A-frag set A (even chunks)
    bf16x8 Ba00, Ba01, Ba10, Ba11;      // A-frag set B (odd chunks)

#define ISSUE_A9(S, ch) do {                                                  \
    const unsigned short* ap_ = wfb + ((size_t)(ch) << 14);                   \
    S##00 = *(const bf16x8*)(ap_);                                            \
    S##01 = *(const bf16x8*)(ap_ + 512);                                      \
    S##10 = *(const bf16x8*)(ap_ + 1024);                                     \
    S##11 = *(const bf16x8*)(ap_ + 1536);                                     \
} while (0)

#define ISSUE_G9(ch, idm) do {                                                \
    int cb_ = (((ch) & 7) << 6) + (grp << 3);                                 \
    v0 = *(const bf16x8*)(ccT + (idm).x + cb_);                               \
    v1 = *(const bf16x8*)(ccT + (idm).y + cb_);                               \
    v2 = *(const bf16x8*)(ccT + (idm).z + cb_);                               \
    v3 = *(const bf16x8*)(ccT + (idm).w + cb_);                               \
} while (0)

#define NEXT_G9(cn) do {                                                      \
    if ((cn) < c1) {                                                          \
        if (((cn) & 7) == 0) {                                                \
            idc = idn; wtc = wtn;                                             \
            int kt2_ = ((cn) >> 3) + 1;                                       \
            if ((kt2_ << 3) < c1) {                                           \
                idn = IDX[(kt2_ << 14) + p2];                                 \
                wtn = WT [(kt2_ << 14) + p2];                                 \
            }                                                                 \
        }                                                                     \
        ISSUE_G9(cn, idc);                                                    \
        wnext = wtc;                                                          \
    }                                                                         \
} while (0)

#define PUBLISH9(bi) do {                                                     \
    unsigned short pk_[8];                                                    \
    _Pragma("unroll")                                                         \
    for (int e_ = 0; e_ < 8; ++e_) {                                          \
        float val_ = wcur.x * bf2f((unsigned short)v0[e_])                    \
                   + wcur.y * bf2f((unsigned short)v1[e_])                    \
                   + wcur.z * bf2f((unsigned short)v2[e_])                    \
                   + wcur.w * bf2f((unsigned short)v3[e_]);                   \
        pk_[e_] = f2bf(val_);                                                 \
    }                                                                         \
    *(bf16x8*)&Bs[bi][pxg][grp << 3] = *(bf16x8*)pk_;                         \
} while (0)

#define MFMA9(S, bi) do {                                                     \
    _Pragma("unroll")                                                         \
    for (int ni_ = 0; ni_ < 4; ++ni_) {                                       \
        bf16x8 b0_ = *(const bf16x8*)(&Bs[bi][(ni_ << 4) + lr][lg << 3]);     \
        acc[0][ni_] = __builtin_amdgcn_mfma_f32_16x16x32_bf16(S##00, b0_, acc[0][ni_], 0, 0, 0); \
        acc[1][ni_] = __builtin_amdgcn_mfma_f32_16x16x32_bf16(S##01, b0_, acc[1][ni_], 0, 0, 0); \
    }                                                                         \
    _Pragma("unroll")                                                         \
    for (int ni_ = 0; ni_ < 4; ++ni_) {                                       \
        bf16x8 b1_ = *(const bf16x8*)(&Bs[bi][(ni_ << 4) + lr][32 + (lg << 3)]); \
        acc[0][ni_] = __builtin_amdgcn_mfma_f32_16x16x32_bf16(S##10, b1_, acc[0][ni_], 0, 0, 0); \
        acc[1][ni_] = __builtin_amdgcn_mfma_f32_16x16x32_bf16(S##11, b1_, acc[1][ni_], 0, 0, 0); \
    }                                                                         \
} while (0)

    int c0 = khalf * 36, c1 = c0 + 36;
    int kt0 = c0 >> 3;
    int4   idc = IDX[(kt0 << 14) + p2];
    float4 wtc = WT [(kt0 << 14) + p2];
    int4   idn = IDX[((kt0 + 1) << 14) + p2];
    float4 wtn = WT [((kt0 + 1) << 14) + p2];
    ISSUE_G9(c0, idc);
    float4 wcur = wtc, wnext = wtc;
    ISSUE_A9(Aa, c0);

    for (int c = c0; c < c1; c += 2) {
        // even chunk c -> Bs[0], consumes Aa
        PUBLISH9(0);                    // weighting of gather(c)
        NEXT_G9(c + 1);                 // gather(c+1) in flight across MFMA(c)
        ISSUE_A9(Ba, c + 1);            // A(c+1) in flight across MFMA(c)
        __syncthreads();                // publish(c) visible; MFMA(c-1) done
        MFMA9(Aa, 0);
        wcur = wnext;
        // odd chunk c+1 -> Bs[1], consumes Ba
        PUBLISH9(1);
        NEXT_G9(c + 2);
        if (c + 2 < c1) ISSUE_A9(Aa, c + 2);
        __syncthreads();
        MFMA9(Ba, 1);
        wcur = wnext;
    }
#undef ISSUE_A9
#undef ISSUE_G9
#undef NEXT_G9
#undef PUBLISH9
#undef MFMA9

    unsigned short* pt = khalf ? part1 : part0;
#pragma unroll
    for (int mi = 0; mi < 2; ++mi)
#pragma unroll
        for (int ni = 0; ni < 4; ++ni) {
            int pxx = pc0 + (ni << 4) + lr;
            int p = (hrow << 7) + pxx;
            unsigned short pk[4];
#pragma unroll
            for (int r = 0; r < 4; ++r) pk[r] = f2bf(acc[mi][ni][r]);
            *(ushort4*)(pt + (size_t)p * 256 + (wv << 5) + (mi << 4) + (lg << 2))
                = *(ushort4*)pk;
        }
}

// ---- famT interior = part0 + part1 + Cf(from ccT), all pixel-major ---------
__global__ __launch_bounds__(256) void combineT_k(
        const unsigned short* __restrict__ p0,    // [HW][256]
        const unsigned short* __restrict__ p1,    // [HW][256]
        const unsigned short* __restrict__ ccT,   // [130*130][512], Cf at +256
        unsigned short* __restrict__ famT) {      // [130*130][256]
    int t = blockIdx.x * 256 + threadIdx.x;       // 524,288 = HW*32
    int o8 = (t & 31) << 3, p = t >> 5;
    int row = p >> 7, col = p & 127;
    int pix = (row + 1) * 130 + col + 1;
    bf16x8 a = *(const bf16x8*)(p0 + (size_t)p * 256 + o8);
    bf16x8 b = *(const bf16x8*)(p1 + (size_t)p * 256 + o8);
    bf16x8 c = *(const bf16x8*)(ccT + (size_t)pix * 512 + 256 + o8);
    unsigned short out[8];
#pragma unroll
    for (int e = 0; e < 8; ++e)
        out[e] = f2bf(bf2f((unsigned short)a[e]) + bf2f((unsigned short)b[e])
                      + bf2f((unsigned short)c[e]));
    *(bf16x8*)(famT + (size_t)pix * 256 + o8) = *(bf16x8*)out;
}

// ============ 3x3 conv 256->256 v2: stage-once pixel-major, 1 barrier =======
__global__ __launch_bounds__(256, 2) void conv2T_k(
        const unsigned short* __restrict__ inT,   // [130*130][256] bf16, ring=0
        const unsigned short* __restrict__ wF,    // frag-major [9][4][8][4][64][8]
        const float* __restrict__ gam, const float* __restrict__ bet,
        const float* __restrict__ mean, const float* __restrict__ var,
        float* __restrict__ out_flat,             // [256][HW] f32
        unsigned short* __restrict__ out_padT) {  // optional [130*130][256]
    __shared__ __align__(16) unsigned short Ls[102][264];   // 53,856 B
    __shared__ float scs[256], bis[256];
    int b = blockIdx.x;
    int xcd = b & 7, slot = b >> 3;
    int nt = (xcd << 6) + slot;
    int hrow = nt >> 2, pc0 = (nt & 3) << 5;
    int tid = threadIdx.x;
    int wv = tid >> 6, lane = tid & 63;
    int lr = lane & 15, lg = lane >> 4;
    {
        float sc = gam[tid] * rsqrtf(var[tid] + 1e-5f);
        scs[tid] = sc;
        bis[tid] = bet[tid] - mean[tid] * sc;
    }
#pragma unroll
    for (int r = 0; r < 3; ++r) {
        const unsigned short* src = inT + (size_t)((hrow + r) * 130 + pc0) * 256;
#pragma unroll
        for (int ps = 0; ps < 5; ++ps) {
            int idx = ps * 2048 + tid * 8;
            if (idx < 8704) {                     // 34*256
                bf16x8 v = *(const bf16x8*)(src + idx);
                *(bf16x8*)&Ls[r * 34 + (idx >> 8)][idx & 255] = v;
            }
        }
    }
    __syncthreads();

    f32x4 acc[4][2];
#pragma unroll
    for (int i = 0; i < 4; ++i)
#pragma unroll
        for (int j = 0; j < 2; ++j) acc[i][j] = (f32x4){0.f, 0.f, 0.f, 0.f};

    const unsigned short* wvb = wF + ((size_t)wv << 14) + ((size_t)lane << 3);
    for (int kt = 0; kt < 9; ++kt) {
        int rowb = (kt / 3) * 34 + (kt % 3);
        const unsigned short* wkb = wvb + (size_t)kt * 65536;
#pragma unroll
        for (int kss = 0; kss < 8; ++kss) {
            int ks = kss << 5;
            bf16x8 af[4], bfr[2];
#pragma unroll
            for (int mi = 0; mi < 4; ++mi)
                af[mi] = *(const bf16x8*)(wkb + (size_t)kss * 2048 + mi * 512);
#pragma unroll
            for (int ni = 0; ni < 2; ++ni)
                bfr[ni] = *(const bf16x8*)(&Ls[rowb + (ni << 4) + lr][ks + (lg << 3)]);
#pragma unroll
            for (int mi = 0; mi < 4; ++mi)
#pragma unroll
                for (int ni = 0; ni < 2; ++ni)
                    acc[mi][ni] = __builtin_amdgcn_mfma_f32_16x16x32_bf16(
                        af[mi], bfr[ni], acc[mi][ni], 0, 0, 0);
        }
    }

#pragma unroll
    for (int mi = 0; mi < 4; ++mi)
#pragma unroll
        for (int ni = 0; ni < 2; ++ni) {
            int pxx = pc0 + (ni << 4) + lr;
            unsigned short pk[4];
#pragma unroll
            for (int r = 0; r < 4; ++r) {
                int o = (wv << 6) + (mi << 4) + (lg << 2) + r;
                float rv = fmaxf(acc[mi][ni][r] * scs[o] + bis[o], 0.0f);
                out_flat[(size_t)o * HW + (hrow << 7) + pxx] = rv;
                pk[r] = f2bf(rv);
            }
            if (out_padT) {
                int pix = (hrow + 1) * 130 + pxx + 1;
                *(ushort4*)(out_padT + (size_t)pix * 256 + (wv << 6) + (mi << 4) + (lg << 2))
                    = *(ushort4*)pk;
            }
        }
}

extern "C" void kernel_launch(void* const* d_in, const int* in_sizes, int n_in,
                              void* d_out, int out_size, void* d_ws, size_t ws_size,
                              hipStream_t stream) {
    const float* x     = (const float*)d_in[0];
    const float* llf   = (const float*)d_in[1];
    const float* fm_w  = (const float*)d_in[2];
    const float* fs_w  = (const float*)d_in[3];
    const float* p_w   = (const float*)d_in[4];
    const float* p_b   = (const float*)d_in[5];
    const float* dc_w  = (const float*)d_in[6];
    const float* lc1_w = (const float*)d_in[7];
    const float* bn1g  = (const float*)d_in[8];
    const float* bn1b  = (const float*)d_in[9];
    const float* bn1m  = (const float*)d_in[10];
    const float* bn1v  = (const float*)d_in[11];
    const float* lc2_w = (const float*)d_in[12];
    const float* bn2g  = (const float*)d_in[13];
    const float* bn2b  = (const float*)d_in[14];
    const float* bn2m  = (const float*)d_in[15];
    const float* bn2v  = (const float*)d_in[16];
    float* out1 = (float*)d_out;
    float* out2 = out1 + (size_t)256 * HW;

    // d_out is WRITE-ONLY (pure outputs). All scratch lives in ws.
    if (ws_size < 79839232u) return;
    char* ws = (char*)d_ws;
    unsigned short* ccT   = (unsigned short*)ws;                // [0, 17,305,600)
    float*          xTf   = (float*)(ws + 17305600);            // 1MB, dead after up_cvtT
    float*          vbuf  = (float*)(ws + 17305600);
    unsigned short* famT  = (unsigned short*)(ws + 17305600);   // [130*130][256]
    unsigned short* up1T  = (unsigned short*)(ws + 26091520);   // [130*130][256]
    unsigned short* llfT  = (unsigned short*)(ws + 34877440);   // dead after vmfma
    unsigned short* uT    = (unsigned short*)(ws + 43266048);   // dead after cfmfma
    unsigned short* part0 = (unsigned short*)(ws + 43266048);   // fam9 partial khalf=0
    unsigned short* fmwh  = (unsigned short*)(ws + 51654656);   // 131,072
    unsigned short* fswh  = (unsigned short*)(ws + 51785728);   // 131,072
    float*          ubuf  = (float*)(ws + 51916800);            // U region
    float*          pbuf  = (float*)(ws + 51916800);            // dead after make_idx
    unsigned short* part1 = (unsigned short*)(ws + 51916800);   // fam9 partial khalf=1
    int4*           IDX   = (int4*)  (ws + 60305408);
    float4*         WT    = (float4*)(ws + 62664704);
    unsigned short* dcwF   = (unsigned short*)(ws + 68694016);  // 2,359,296 (frag-major)
    unsigned short* lcw1F  = (unsigned short*)(ws + 71053312);  // 1,179,648
    unsigned short* lcw2F  = (unsigned short*)(ws + 72232960);  // 1,179,648
    unsigned short* pwTh   = (unsigned short*)(ws + 73412608);  //   294,912

    xT_k<<<dim3(1024), 256, 0, stream>>>(x, xTf);
    up_cvtT_k<<<dim3(16900), 256, 0, stream>>>(xTf, ccT);         // ccT ch 0..255 (+ring0)
    cvtT_tile_k<<<dim3(256, 4), 256, 0, stream>>>(llf, llfT);
    w2bf_k<<<dim3(256), 256, 0, stream>>>(fm_w, fs_w, fmwh, fswh);
    vmfma2_k<<<dim3(512), 256, 0, stream>>>(llfT, fmwh, vbuf);    // llfT dead after
    u_matmul_k<<<dim3(2, 256), 256, 0, stream>>>(llf, vbuf, ubuf);  // vbuf dead after
    cvtT_tile_k<<<dim3(256, 4), 256, 0, stream>>>(ubuf, uT);      // ubuf dead after
    tr_dcwF9_k<<<dim3(4608), 256, 0, stream>>>(dc_w, dcwF);       // wave-slice frag-major
    tr_lcF2_k<<<dim3(2304, 2), 256, 0, stream>>>(lc1_w, lc2_w, lcw1F, lcw2F);
    tr_pw_k<<<dim3(576), 256, 0, stream>>>(p_w, pwTh);
    cfmfma2_k<<<dim3(512), 256, 0, stream>>>(uT, fswh, ccT);      // uT dead after
    ringT_k<<<dim3(520), 256, 0, stream>>>(ccT);                  // Cf ring = 0
    off_part2h_k<<<dim3(512), 256, 0, stream>>>(ccT, pwTh, pbuf);
    make_idx_k<<<dim3(576), 256, 0, stream>>>(pbuf, p_b, IDX, WT);  // pbuf dead after
    zero_ringP2_k<<<dim3(130), 256, 0, stream>>>(famT, up1T);
    fam9_k<<<dim3(512), 512, 0, stream>>>(ccT, dcwF, IDX, WT, part0, part1);
    combineT_k<<<dim3(2048), 256, 0, stream>>>(part0, part1, ccT, famT);
    conv2T_k<<<dim3(512), 256, 0, stream>>>(famT, lcw1F, bn1g, bn1b, bn1m, bn1v,
                                            out1, up1T);
    conv2T_k<<<dim3(512), 256, 0, stream>>>(up1T, lcw2F, bn2g, bn2b, bn2m, bn2v,
                                            out2, nullptr);
}